// Round 1
// baseline (983.035 us; speedup 1.0000x reference)
//
#include <hip/hip_runtime.h>

#define N_NODES 50000
#define FEAT    128
#define NZ      64
#define IN_DIM  192
#define HDIM    256
#define E_EDGES 800000
#define BN_EPS  1e-5f
#define SLOPE   0.2f

// ---------------------------------------------------------------------------
// Scatter: for each edge e, agg[dst] += x[src]  (x = concat(nf, noise) read
// directly from the two source arrays), deg[dst] += 1.
// One 64-lane wave per edge; lane l handles channels {l, l+64, l+128}.
// ---------------------------------------------------------------------------
__global__ __launch_bounds__(256) void scatter_kernel(
    const float* __restrict__ nf, const float* __restrict__ noise,
    const int* __restrict__ ei, float* __restrict__ agg, float* __restrict__ deg) {
  int g = blockIdx.x * blockDim.x + threadIdx.x;
  int lane = g & 63;
  int group = g >> 6;
  int ngroups = (gridDim.x * blockDim.x) >> 6;
  for (int e = group; e < E_EDGES; e += ngroups) {
    int src = ei[e];
    int dst = ei[E_EDGES + e];
    float v0 = nf[(size_t)src * FEAT + lane];
    float v1 = nf[(size_t)src * FEAT + 64 + lane];
    float v2 = noise[(size_t)src * NZ + lane];
    float* ar = agg + (size_t)dst * IN_DIM;
    atomicAdd(ar + lane, v0);
    atomicAdd(ar + 64 + lane, v1);
    atomicAdd(ar + 128 + lane, v2);
    if (lane == 0) atomicAdd(deg + dst, 1.0f);
  }
}

// ---------------------------------------------------------------------------
// Combine: h = lrelu(BN(mean_agg @ W_l + b_l + x @ W_r))
// 32-row tile in LDS (x read from nf/noise, agg scaled by 1/max(deg,1) on
// load). 256 threads = one output column each; 32 row-accumulators/thread.
// LDS reads are wave-broadcast (all lanes same address) -> conflict-free.
// ---------------------------------------------------------------------------
__global__ __launch_bounds__(256) void combine_kernel(
    const float* __restrict__ nf, const float* __restrict__ noise,
    const float* __restrict__ agg, const float* __restrict__ deg,
    const float* __restrict__ Wl, const float* __restrict__ bl,
    const float* __restrict__ Wr,
    const float* __restrict__ gamma, const float* __restrict__ beta,
    const float* __restrict__ mean, const float* __restrict__ var,
    float* __restrict__ h) {
  __shared__ float xs[32 * IN_DIM];
  __shared__ float as[32 * IN_DIM];
  __shared__ float rd[32];
  const int tid = threadIdx.x;
  const int r0 = blockIdx.x * 32;

  if (tid < 32) {
    int gr = r0 + tid;
    float d = (gr < N_NODES) ? deg[gr] : 1.0f;
    rd[tid] = 1.0f / fmaxf(d, 1.0f);
  }
  __syncthreads();

  // 32 rows * 48 float4 per row = 1536 float4
  for (int i = tid; i < 32 * 48; i += 256) {
    int row = i / 48, c4 = i % 48;
    int gr = r0 + row;
    float4 xv = make_float4(0.f, 0.f, 0.f, 0.f);
    float4 av = make_float4(0.f, 0.f, 0.f, 0.f);
    if (gr < N_NODES) {
      if (c4 < 32) xv = ((const float4*)nf)[(size_t)gr * 32 + c4];
      else         xv = ((const float4*)noise)[(size_t)gr * 16 + (c4 - 32)];
      av = ((const float4*)agg)[(size_t)gr * 48 + c4];
      float s = rd[row];
      av.x *= s; av.y *= s; av.z *= s; av.w *= s;
    }
    ((float4*)xs)[i] = xv;
    ((float4*)as)[i] = av;
  }
  __syncthreads();

  const int c = tid;  // output column 0..255
  float acc[32];
#pragma unroll
  for (int i = 0; i < 32; ++i) acc[i] = 0.f;

  for (int k0 = 0; k0 < IN_DIM; k0 += 4) {
    float wl0 = Wl[(k0 + 0) * HDIM + c];
    float wl1 = Wl[(k0 + 1) * HDIM + c];
    float wl2 = Wl[(k0 + 2) * HDIM + c];
    float wl3 = Wl[(k0 + 3) * HDIM + c];
    float wr0 = Wr[(k0 + 0) * HDIM + c];
    float wr1 = Wr[(k0 + 1) * HDIM + c];
    float wr2 = Wr[(k0 + 2) * HDIM + c];
    float wr3 = Wr[(k0 + 3) * HDIM + c];
#pragma unroll
    for (int i = 0; i < 32; ++i) {
      float4 a = *(const float4*)&xs[i * IN_DIM + k0];
      float4 gv = *(const float4*)&as[i * IN_DIM + k0];
      acc[i] += a.x * wr0 + a.y * wr1 + a.z * wr2 + a.w * wr3
              + gv.x * wl0 + gv.y * wl1 + gv.z * wl2 + gv.w * wl3;
    }
  }

  const float sc = gamma[c] * rsqrtf(var[c] + BN_EPS);
  const float sh = beta[c] - mean[c] * sc;
  const float bb = bl[c];
#pragma unroll
  for (int i = 0; i < 32; ++i) {
    int gr = r0 + i;
    if (gr < N_NODES) {
      float v = (acc[i] + bb) * sc + sh;
      h[(size_t)gr * HDIM + c] = (v >= 0.f) ? v : SLOPE * v;
    }
  }
}

// ---------------------------------------------------------------------------
// Generic fc layer: out[N,M] = lrelu(in[N,K] @ W[K,M] + b)
// 64-row LDS tile, 256 threads = (M columns) x (256/M row-groups).
// ---------------------------------------------------------------------------
template <int K, int M>
__global__ __launch_bounds__(256) void fc_kernel(
    const float* __restrict__ in, const float* __restrict__ W,
    const float* __restrict__ b, float* __restrict__ out) {
  constexpr int RG = 256 / M;   // row groups
  constexpr int RPT = 64 / RG;  // rows per thread
  constexpr int K4 = K / 4;
  __shared__ float s[64 * K];
  const int tid = threadIdx.x;
  const int r0 = blockIdx.x * 64;

  for (int i = tid; i < 64 * K4; i += 256) {
    int gr = r0 + i / K4;
    float4 v = make_float4(0.f, 0.f, 0.f, 0.f);
    if (gr < N_NODES) v = ((const float4*)in)[(size_t)gr * K4 + (i % K4)];
    ((float4*)s)[i] = v;
  }
  __syncthreads();

  const int c = tid % M;
  const int rbase = (tid / M) * RPT;
  float acc[RPT];
#pragma unroll
  for (int i = 0; i < RPT; ++i) acc[i] = 0.f;

  for (int k0 = 0; k0 < K; k0 += 4) {
    float w0 = W[(k0 + 0) * M + c];
    float w1 = W[(k0 + 1) * M + c];
    float w2 = W[(k0 + 2) * M + c];
    float w3 = W[(k0 + 3) * M + c];
#pragma unroll
    for (int i = 0; i < RPT; ++i) {
      float4 a = *(const float4*)&s[(rbase + i) * K + k0];
      acc[i] += a.x * w0 + a.y * w1 + a.z * w2 + a.w * w3;
    }
  }

  const float bb = b[c];
#pragma unroll
  for (int i = 0; i < RPT; ++i) {
    int gr = r0 + rbase + i;
    if (gr < N_NODES) {
      float v = acc[i] + bb;
      out[(size_t)gr * M + c] = (v >= 0.f) ? v : SLOPE * v;
    }
  }
}

extern "C" void kernel_launch(void* const* d_in, const int* in_sizes, int n_in,
                              void* d_out, int out_size, void* d_ws, size_t ws_size,
                              hipStream_t stream) {
  const float* nf    = (const float*)d_in[0];
  const float* noise = (const float*)d_in[1];
  const int*   ei    = (const int*)d_in[2];
  // d_in[3] = batch (unused at inference)
  const float* Wl    = (const float*)d_in[4];
  const float* bl    = (const float*)d_in[5];
  const float* Wr    = (const float*)d_in[6];
  const float* gam   = (const float*)d_in[7];
  const float* bet   = (const float*)d_in[8];
  const float* bmean = (const float*)d_in[9];
  const float* bvar  = (const float*)d_in[10];
  const float* fc1w  = (const float*)d_in[11];
  const float* fc1b  = (const float*)d_in[12];
  const float* fc2w  = (const float*)d_in[13];
  const float* fc2b  = (const float*)d_in[14];
  const float* fc3w  = (const float*)d_in[15];
  const float* fc3b  = (const float*)d_in[16];
  const float* fc4w  = (const float*)d_in[17];
  const float* fc4b  = (const float*)d_in[18];
  float* outp = (float*)d_out;

  // Workspace layout (floats). N*192 and N are both multiples of 4 -> 16B aligned.
  float* ws  = (float*)d_ws;
  float* agg = ws;                          // N*192
  float* deg = agg + (size_t)N_NODES * IN_DIM;  // N
  float* h   = deg + N_NODES;               // N*256
  // Reuse after their producers are dead:
  float* h1 = agg;                          // N*128 (agg dead after combine)... careful: see below
  float* h2 = agg + (size_t)N_NODES * 128;  // N*64  (within agg+deg region? no: fits in N*192 region)
  float* h3 = h;                            // N*64  (h dead after fc1)

  // NOTE: h1 occupies agg[0 .. N*128); h2 occupies agg[N*128 .. N*192). Both
  // fit inside the original agg region (N*192 floats) with no overlap.

  hipMemsetAsync(agg, 0, (size_t)N_NODES * IN_DIM * sizeof(float), stream);
  hipMemsetAsync(deg, 0, (size_t)N_NODES * sizeof(float), stream);

  // Scatter: 6250 blocks * 256 thr = 25000 waves, 32 edges each.
  scatter_kernel<<<6250, 256, 0, stream>>>(nf, noise, ei, agg, deg);

  // Combine: 32-row tiles.
  combine_kernel<<<(N_NODES + 31) / 32, 256, 0, stream>>>(
      nf, noise, agg, deg, Wl, bl, Wr, gam, bet, bmean, bvar, h);

  // fc1: [N,256]@[256,128] — reads h, writes h1 (agg region; agg dead).
  fc_kernel<256, 128><<<(N_NODES + 63) / 64, 256, 0, stream>>>(h, fc1w, fc1b, h1);
  // fc2: [N,128]@[128,64] — reads h1, writes h2 (agg region upper part).
  fc_kernel<128, 64><<<(N_NODES + 63) / 64, 256, 0, stream>>>(h1, fc2w, fc2b, h2);
  // fc3: [N,64]@[64,64] — reads h2, writes h3 (h region; h dead after fc1).
  fc_kernel<64, 64><<<(N_NODES + 63) / 64, 256, 0, stream>>>(h2, fc3w, fc3b, h3);
  // fc4: [N,64]@[64,128] — reads h3, writes final output.
  fc_kernel<64, 128><<<(N_NODES + 63) / 64, 256, 0, stream>>>(h3, fc4w, fc4b, outp);
}

// Round 2
// 620.882 us; speedup vs baseline: 1.5833x; 1.5833x over previous
//
#include <hip/hip_runtime.h>

#define N_NODES 50000
#define FEAT    128
#define NZ      64
#define IN_DIM  192
#define HDIM    256
#define E_EDGES 800000
#define BN_EPS  1e-5f
#define SLOPE   0.2f
#define NB      196   // ceil(N_NODES / 256)

// ---------------------------------------------------------------------------
// CSR build, step 1: degree count (int atomics on 50k counters).
// ---------------------------------------------------------------------------
__global__ __launch_bounds__(256) void deg_count_kernel(
    const int* __restrict__ ei, int* __restrict__ deg) {
  int e = blockIdx.x * blockDim.x + threadIdx.x;
  if (e < E_EDGES) atomicAdd(&deg[ei[E_EDGES + e]], 1);
}

// Step 2: per-256-chunk sums.
__global__ __launch_bounds__(256) void block_sum_kernel(
    const int* __restrict__ deg, int* __restrict__ bsum) {
  __shared__ int sh[256];
  int i = blockIdx.x * 256 + threadIdx.x;
  sh[threadIdx.x] = (i < N_NODES) ? deg[i] : 0;
  __syncthreads();
  for (int s = 128; s > 0; s >>= 1) {
    if (threadIdx.x < s) sh[threadIdx.x] += sh[threadIdx.x + s];
    __syncthreads();
  }
  if (threadIdx.x == 0) bsum[blockIdx.x] = sh[0];
}

// Step 3: exclusive scan of the 196 chunk sums (single block).
__global__ __launch_bounds__(256) void scan_bsum_kernel(int* __restrict__ bsum) {
  __shared__ int sh[256];
  int t = threadIdx.x;
  sh[t] = (t < NB) ? bsum[t] : 0;
  __syncthreads();
  for (int off = 1; off < 256; off <<= 1) {
    int v = (t >= off) ? sh[t - off] : 0;
    __syncthreads();
    sh[t] += v;
    __syncthreads();
  }
  if (t < NB) bsum[t] = (t == 0) ? 0 : sh[t - 1];
}

// Step 4: per-chunk exclusive scan + chunk base -> cursor[i] = row start.
__global__ __launch_bounds__(256) void scan_chunk_kernel(
    const int* __restrict__ deg, const int* __restrict__ bsum,
    int* __restrict__ cursor) {
  __shared__ int sh[256];
  int t = threadIdx.x;
  int i = blockIdx.x * 256 + t;
  int v = (i < N_NODES) ? deg[i] : 0;
  sh[t] = v;
  __syncthreads();
  for (int off = 1; off < 256; off <<= 1) {
    int u = (t >= off) ? sh[t - off] : 0;
    __syncthreads();
    sh[t] += u;
    __syncthreads();
  }
  if (i < N_NODES) cursor[i] = bsum[blockIdx.x] + sh[t] - v;  // exclusive
}

// Step 5: fill CSR. After this, cursor[i] == row_end(i); start = end - deg[i].
__global__ __launch_bounds__(256) void fill_kernel(
    const int* __restrict__ ei, int* __restrict__ cursor, int* __restrict__ csr) {
  int e = blockIdx.x * blockDim.x + threadIdx.x;
  if (e < E_EDGES) {
    int src = ei[e];
    int dst = ei[E_EDGES + e];
    int p = atomicAdd(&cursor[dst], 1);
    csr[p] = src;
  }
}

// ---------------------------------------------------------------------------
// Gather-aggregate: one wave per node. Lane l sums channels {l, l+64, l+128}
// over the neighbor list (2-way unrolled, dual accumulators), divides by deg,
// writes mean_agg once. No feature atomics.
// ---------------------------------------------------------------------------
__global__ __launch_bounds__(256) void gather_kernel(
    const float* __restrict__ nf, const float* __restrict__ noise,
    const int* __restrict__ csr, const int* __restrict__ cursor,
    const int* __restrict__ deg, float* __restrict__ mean_agg) {
  int wid = (blockIdx.x * blockDim.x + threadIdx.x) >> 6;
  int lane = threadIdx.x & 63;
  if (wid >= N_NODES) return;
  int d = deg[wid];
  int end = cursor[wid];
  int start = end - d;

  float a0 = 0.f, a1 = 0.f, a2 = 0.f;
  float b0 = 0.f, b1 = 0.f, b2 = 0.f;
  int j = start;
  for (; j + 1 < end; j += 2) {
    int sa = csr[j];
    int sb = csr[j + 1];
    a0 += nf[(size_t)sa * FEAT + lane];
    b0 += nf[(size_t)sb * FEAT + lane];
    a1 += nf[(size_t)sa * FEAT + 64 + lane];
    b1 += nf[(size_t)sb * FEAT + 64 + lane];
    a2 += noise[(size_t)sa * NZ + lane];
    b2 += noise[(size_t)sb * NZ + lane];
  }
  if (j < end) {
    int sa = csr[j];
    a0 += nf[(size_t)sa * FEAT + lane];
    a1 += nf[(size_t)sa * FEAT + 64 + lane];
    a2 += noise[(size_t)sa * NZ + lane];
  }
  float inv = 1.0f / fmaxf((float)d, 1.0f);
  mean_agg[(size_t)wid * IN_DIM + lane]       = (a0 + b0) * inv;
  mean_agg[(size_t)wid * IN_DIM + 64 + lane]  = (a1 + b1) * inv;
  mean_agg[(size_t)wid * IN_DIM + 128 + lane] = (a2 + b2) * inv;
}

// ---------------------------------------------------------------------------
// Combine: h = lrelu(BN(mean_agg @ W_l + b_l + x @ W_r))
// ---------------------------------------------------------------------------
__global__ __launch_bounds__(256) void combine_kernel(
    const float* __restrict__ nf, const float* __restrict__ noise,
    const float* __restrict__ mean_agg,
    const float* __restrict__ Wl, const float* __restrict__ bl,
    const float* __restrict__ Wr,
    const float* __restrict__ gamma, const float* __restrict__ beta,
    const float* __restrict__ mean, const float* __restrict__ var,
    float* __restrict__ h) {
  __shared__ float xs[32 * IN_DIM];
  __shared__ float as[32 * IN_DIM];
  const int tid = threadIdx.x;
  const int r0 = blockIdx.x * 32;

  for (int i = tid; i < 32 * 48; i += 256) {
    int c4 = i % 48;
    int gr = r0 + i / 48;
    float4 xv = make_float4(0.f, 0.f, 0.f, 0.f);
    float4 av = make_float4(0.f, 0.f, 0.f, 0.f);
    if (gr < N_NODES) {
      if (c4 < 32) xv = ((const float4*)nf)[(size_t)gr * 32 + c4];
      else         xv = ((const float4*)noise)[(size_t)gr * 16 + (c4 - 32)];
      av = ((const float4*)mean_agg)[(size_t)gr * 48 + c4];
    }
    ((float4*)xs)[i] = xv;
    ((float4*)as)[i] = av;
  }
  __syncthreads();

  const int c = tid;
  float acc[32];
#pragma unroll
  for (int i = 0; i < 32; ++i) acc[i] = 0.f;

  for (int k0 = 0; k0 < IN_DIM; k0 += 4) {
    float wl0 = Wl[(k0 + 0) * HDIM + c];
    float wl1 = Wl[(k0 + 1) * HDIM + c];
    float wl2 = Wl[(k0 + 2) * HDIM + c];
    float wl3 = Wl[(k0 + 3) * HDIM + c];
    float wr0 = Wr[(k0 + 0) * HDIM + c];
    float wr1 = Wr[(k0 + 1) * HDIM + c];
    float wr2 = Wr[(k0 + 2) * HDIM + c];
    float wr3 = Wr[(k0 + 3) * HDIM + c];
#pragma unroll
    for (int i = 0; i < 32; ++i) {
      float4 a = *(const float4*)&xs[i * IN_DIM + k0];
      float4 gv = *(const float4*)&as[i * IN_DIM + k0];
      acc[i] += a.x * wr0 + a.y * wr1 + a.z * wr2 + a.w * wr3
              + gv.x * wl0 + gv.y * wl1 + gv.z * wl2 + gv.w * wl3;
    }
  }

  const float sc = gamma[c] * rsqrtf(var[c] + BN_EPS);
  const float sh = beta[c] - mean[c] * sc;
  const float bb = bl[c];
#pragma unroll
  for (int i = 0; i < 32; ++i) {
    int gr = r0 + i;
    if (gr < N_NODES) {
      float v = (acc[i] + bb) * sc + sh;
      h[(size_t)gr * HDIM + c] = (v >= 0.f) ? v : SLOPE * v;
    }
  }
}

// ---------------------------------------------------------------------------
// Generic fc layer: out[N,M] = lrelu(in[N,K] @ W[K,M] + b)
// ---------------------------------------------------------------------------
template <int K, int M>
__global__ __launch_bounds__(256) void fc_kernel(
    const float* __restrict__ in, const float* __restrict__ W,
    const float* __restrict__ b, float* __restrict__ out) {
  constexpr int RG = 256 / M;
  constexpr int RPT = 64 / RG;
  constexpr int K4 = K / 4;
  __shared__ float s[64 * K];
  const int tid = threadIdx.x;
  const int r0 = blockIdx.x * 64;

  for (int i = tid; i < 64 * K4; i += 256) {
    int gr = r0 + i / K4;
    float4 v = make_float4(0.f, 0.f, 0.f, 0.f);
    if (gr < N_NODES) v = ((const float4*)in)[(size_t)gr * K4 + (i % K4)];
    ((float4*)s)[i] = v;
  }
  __syncthreads();

  const int c = tid % M;
  const int rbase = (tid / M) * RPT;
  float acc[RPT];
#pragma unroll
  for (int i = 0; i < RPT; ++i) acc[i] = 0.f;

  for (int k0 = 0; k0 < K; k0 += 4) {
    float w0 = W[(k0 + 0) * M + c];
    float w1 = W[(k0 + 1) * M + c];
    float w2 = W[(k0 + 2) * M + c];
    float w3 = W[(k0 + 3) * M + c];
#pragma unroll
    for (int i = 0; i < RPT; ++i) {
      float4 a = *(const float4*)&s[(rbase + i) * K + k0];
      acc[i] += a.x * w0 + a.y * w1 + a.z * w2 + a.w * w3;
    }
  }

  const float bb = b[c];
#pragma unroll
  for (int i = 0; i < RPT; ++i) {
    int gr = r0 + rbase + i;
    if (gr < N_NODES) {
      float v = acc[i] + bb;
      out[(size_t)gr * M + c] = (v >= 0.f) ? v : SLOPE * v;
    }
  }
}

extern "C" void kernel_launch(void* const* d_in, const int* in_sizes, int n_in,
                              void* d_out, int out_size, void* d_ws, size_t ws_size,
                              hipStream_t stream) {
  const float* nf    = (const float*)d_in[0];
  const float* noise = (const float*)d_in[1];
  const int*   ei    = (const int*)d_in[2];
  const float* Wl    = (const float*)d_in[4];
  const float* bl    = (const float*)d_in[5];
  const float* Wr    = (const float*)d_in[6];
  const float* gam   = (const float*)d_in[7];
  const float* bet   = (const float*)d_in[8];
  const float* bmean = (const float*)d_in[9];
  const float* bvar  = (const float*)d_in[10];
  const float* fc1w  = (const float*)d_in[11];
  const float* fc1b  = (const float*)d_in[12];
  const float* fc2w  = (const float*)d_in[13];
  const float* fc2b  = (const float*)d_in[14];
  const float* fc3w  = (const float*)d_in[15];
  const float* fc3b  = (const float*)d_in[16];
  const float* fc4w  = (const float*)d_in[17];
  const float* fc4b  = (const float*)d_in[18];
  float* outp = (float*)d_out;

  // Workspace layout (4-byte units; all blocks 16B-aligned).
  float* ws       = (float*)d_ws;
  float* mean_agg = ws;                                    // N*192 f
  float* h        = mean_agg + (size_t)N_NODES * IN_DIM;   // N*256 f
  int*   deg      = (int*)(h + (size_t)N_NODES * HDIM);    // N i
  int*   cursor   = deg + N_NODES;                         // N i
  int*   bsum     = cursor + N_NODES;                      // 256 i
  int*   csr      = bsum + 256;                            // E i
  // GEMM-stage aliases (producers dead by then):
  float* h1 = mean_agg;                         // N*128 (mean_agg dead after combine)
  float* h2 = mean_agg + (size_t)N_NODES * 128; // N*64  (rest of mean_agg region)
  float* h3 = h;                                // N*64  (h dead after fc1)

  hipMemsetAsync(deg, 0, (size_t)N_NODES * sizeof(int), stream);

  // --- CSR build ---
  deg_count_kernel<<<(E_EDGES + 255) / 256, 256, 0, stream>>>(ei, deg);
  block_sum_kernel<<<NB, 256, 0, stream>>>(deg, bsum);
  scan_bsum_kernel<<<1, 256, 0, stream>>>(bsum);
  scan_chunk_kernel<<<NB, 256, 0, stream>>>(deg, bsum, cursor);
  fill_kernel<<<(E_EDGES + 255) / 256, 256, 0, stream>>>(ei, cursor, csr);

  // --- Aggregate (one wave per node) ---
  gather_kernel<<<(N_NODES + 3) / 4, 256, 0, stream>>>(
      nf, noise, csr, cursor, deg, mean_agg);

  // --- Combine + MLP stack ---
  combine_kernel<<<(N_NODES + 31) / 32, 256, 0, stream>>>(
      nf, noise, mean_agg, Wl, bl, Wr, gam, bet, bmean, bvar, h);
  fc_kernel<256, 128><<<(N_NODES + 63) / 64, 256, 0, stream>>>(h, fc1w, fc1b, h1);
  fc_kernel<128, 64><<<(N_NODES + 63) / 64, 256, 0, stream>>>(h1, fc2w, fc2b, h2);
  fc_kernel<64, 64><<<(N_NODES + 63) / 64, 256, 0, stream>>>(h2, fc3w, fc3b, h3);
  fc_kernel<64, 128><<<(N_NODES + 63) / 64, 256, 0, stream>>>(h3, fc4w, fc4b, outp);
}

// Round 3
// 350.643 us; speedup vs baseline: 2.8035x; 1.7707x over previous
//
#include <hip/hip_runtime.h>

#define N_NODES 50000
#define NPAD    50048   // 391 * 128
#define FEAT    128
#define NZ      64
#define IN_DIM  192
#define HDIM    256
#define E_EDGES 800000
#define BN_EPS  1e-5f
#define SLOPE   0.2f
#define NB      196     // ceil(N_NODES / 256)

typedef __attribute__((ext_vector_type(8))) short short8v;
typedef __attribute__((ext_vector_type(4))) float f32x4;

// ---------------- bf16 helpers (RNE) ----------------
__device__ __forceinline__ unsigned short f2bf(float v) {
  union { float f; unsigned u; } c; c.f = v;
  unsigned r = c.u + 0x7FFFu + ((c.u >> 16) & 1u);
  return (unsigned short)(r >> 16);
}
__device__ __forceinline__ float bf2f(unsigned short h) {
  union { unsigned u; float f; } c; c.u = ((unsigned)h) << 16; return c.f;
}
__device__ __forceinline__ unsigned short bflo(float v) {
  unsigned short h = f2bf(v);
  return f2bf(v - bf2f(h));
}

__device__ __forceinline__ void gload16(const void* src, const void* lds) {
  __builtin_amdgcn_global_load_lds(
      (const __attribute__((address_space(1))) unsigned int*)src,
      (__attribute__((address_space(3))) unsigned int*)lds, 16, 0, 0);
}

// ---------------------------------------------------------------------------
// CSR build (unchanged from round 2; csr lives in d_out scratch)
// ---------------------------------------------------------------------------
__global__ __launch_bounds__(256) void deg_count_kernel(
    const int* __restrict__ ei, int* __restrict__ deg) {
  int e = blockIdx.x * blockDim.x + threadIdx.x;
  if (e < E_EDGES) atomicAdd(&deg[ei[E_EDGES + e]], 1);
}

__global__ __launch_bounds__(256) void block_sum_kernel(
    const int* __restrict__ deg, int* __restrict__ bsum) {
  __shared__ int sh[256];
  int i = blockIdx.x * 256 + threadIdx.x;
  sh[threadIdx.x] = (i < N_NODES) ? deg[i] : 0;
  __syncthreads();
  for (int s = 128; s > 0; s >>= 1) {
    if (threadIdx.x < s) sh[threadIdx.x] += sh[threadIdx.x + s];
    __syncthreads();
  }
  if (threadIdx.x == 0) bsum[blockIdx.x] = sh[0];
}

__global__ __launch_bounds__(256) void scan_bsum_kernel(int* __restrict__ bsum) {
  __shared__ int sh[256];
  int t = threadIdx.x;
  sh[t] = (t < NB) ? bsum[t] : 0;
  __syncthreads();
  for (int off = 1; off < 256; off <<= 1) {
    int v = (t >= off) ? sh[t - off] : 0;
    __syncthreads();
    sh[t] += v;
    __syncthreads();
  }
  if (t < NB) bsum[t] = (t == 0) ? 0 : sh[t - 1];
}

__global__ __launch_bounds__(256) void scan_chunk_kernel(
    const int* __restrict__ deg, const int* __restrict__ bsum,
    int* __restrict__ cursor) {
  __shared__ int sh[256];
  int t = threadIdx.x;
  int i = blockIdx.x * 256 + t;
  int v = (i < N_NODES) ? deg[i] : 0;
  sh[t] = v;
  __syncthreads();
  for (int off = 1; off < 256; off <<= 1) {
    int u = (t >= off) ? sh[t - off] : 0;
    __syncthreads();
    sh[t] += u;
    __syncthreads();
  }
  if (i < N_NODES) cursor[i] = bsum[blockIdx.x] + sh[t] - v;
}

__global__ __launch_bounds__(256) void fill_kernel(
    const int* __restrict__ ei, int* __restrict__ cursor, int* __restrict__ csr) {
  int e = blockIdx.x * blockDim.x + threadIdx.x;
  if (e < E_EDGES) {
    int src = ei[e];
    int dst = ei[E_EDGES + e];
    int p = atomicAdd(&cursor[dst], 1);
    csr[p] = src;
  }
}

// ---------------------------------------------------------------------------
// Gather-aggregate: one wave per node; writes mean_agg as hi/lo bf16 blocks:
// agg'[n][0..191] = hi, agg'[n][192..383] = lo.
// ---------------------------------------------------------------------------
__global__ __launch_bounds__(256) void gather_kernel(
    const float* __restrict__ nf, const float* __restrict__ noise,
    const int* __restrict__ csr, const int* __restrict__ cursor,
    const int* __restrict__ deg, unsigned short* __restrict__ aggp) {
  int wid = (blockIdx.x * blockDim.x + threadIdx.x) >> 6;
  int lane = threadIdx.x & 63;
  if (wid >= N_NODES) return;
  int d = deg[wid];
  int end = cursor[wid];
  int start = end - d;

  float a0 = 0.f, a1 = 0.f, a2 = 0.f;
  float b0 = 0.f, b1 = 0.f, b2 = 0.f;
  int j = start;
  for (; j + 1 < end; j += 2) {
    int sa = csr[j];
    int sb = csr[j + 1];
    a0 += nf[(size_t)sa * FEAT + lane];
    b0 += nf[(size_t)sb * FEAT + lane];
    a1 += nf[(size_t)sa * FEAT + 64 + lane];
    b1 += nf[(size_t)sb * FEAT + 64 + lane];
    a2 += noise[(size_t)sa * NZ + lane];
    b2 += noise[(size_t)sb * NZ + lane];
  }
  if (j < end) {
    int sa = csr[j];
    a0 += nf[(size_t)sa * FEAT + lane];
    a1 += nf[(size_t)sa * FEAT + 64 + lane];
    a2 += noise[(size_t)sa * NZ + lane];
  }
  float inv = 1.0f / fmaxf((float)d, 1.0f);
  float m0 = (a0 + b0) * inv, m1 = (a1 + b1) * inv, m2 = (a2 + b2) * inv;
  unsigned short* ap = aggp + (size_t)wid * 384;
  ap[lane]        = f2bf(m0);  ap[192 + lane] = bflo(m0);
  ap[64 + lane]   = f2bf(m1);  ap[256 + lane] = bflo(m1);
  ap[128 + lane]  = f2bf(m2);  ap[320 + lane] = bflo(m2);
}

// ---------------------------------------------------------------------------
// W conversion: W[K][M] f32 -> W'[M][ld] bf16 rows [hi | hi | lo] (split-GEMM
// B operand, transposed to col-major-along-K so B-frag reads are contiguous).
// ---------------------------------------------------------------------------
__global__ __launch_bounds__(256) void wconv_kernel(
    const float* __restrict__ Wl, const float* __restrict__ Wr,
    const float* __restrict__ W1, const float* __restrict__ W2,
    const float* __restrict__ W3, const float* __restrict__ W4,
    unsigned short* __restrict__ Wc_, unsigned short* __restrict__ W1_,
    unsigned short* __restrict__ W2_, unsigned short* __restrict__ W3_,
    unsigned short* __restrict__ W4_) {
  int idx = blockIdx.x * 256 + threadIdx.x;
  const float* src; unsigned short* dst;
  int K, M, ld, oh1, oh2, ol, local;
  if      (idx < 49152)  { src=Wl; dst=Wc_; K=192; M=256; ld=1152; oh1=0;   oh2=384; ol=768; local=idx; }
  else if (idx < 98304)  { src=Wr; dst=Wc_; K=192; M=256; ld=1152; oh1=192; oh2=576; ol=960; local=idx-49152; }
  else if (idx < 131072) { src=W1; dst=W1_; K=256; M=128; ld=768;  oh1=0;   oh2=256; ol=512; local=idx-98304; }
  else if (idx < 139264) { src=W2; dst=W2_; K=128; M=64;  ld=384;  oh1=0;   oh2=128; ol=256; local=idx-131072; }
  else if (idx < 143360) { src=W3; dst=W3_; K=64;  M=64;  ld=192;  oh1=0;   oh2=64;  ol=128; local=idx-139264; }
  else if (idx < 151552) { src=W4; dst=W4_; K=64;  M=128; ld=192;  oh1=0;   oh2=64;  ol=128; local=idx-143360; }
  else return;
  int k = local % K, m = local / K;
  float v = src[(size_t)k * M + m];
  unsigned short h = f2bf(v);
  unsigned short l = f2bf(v - bf2f(h));
  size_t base = (size_t)m * ld;
  dst[base + oh1 + k] = h;
  dst[base + oh2 + k] = h;
  dst[base + ol  + k] = l;
}

// ---------------------------------------------------------------------------
// Split-bf16 MFMA GEMM. A' [NPAD][K2A] bf16 blocks [a_hi | a_lo];
// B' [MTOT][K2B] bf16 rows [w_hi | w_hi | w_lo] (K2B = 3K). K-loop runs K2B;
// A col = k0 (mod K2A). Exact terms: a_hi*w_hi + a_lo*w_hi + a_hi*w_lo.
// Tiles: BM=128 rows x MTILE cols, BK=64, 4 waves (2x2), 16x16x32 MFMA.
// LDS rows are 128B with XOR-16B-slot swizzle (T2); A/B staged via
// global_load_lds with pre-swizzled source (rule #21). XSTAGE: combine's x
// half is reg-staged from nf/noise with on-the-fly hi/lo conversion.
// OUT_MODE: 0 = BN+lrelu+bf16pair, 1 = bias+lrelu+bf16pair, 2 = bias+lrelu+f32.
// ---------------------------------------------------------------------------
template <int K2A, int K2B, int MTOT, int MTILE, int OUT_MODE, bool XSTAGE>
__global__ __launch_bounds__(256) void gemm_split(
    const unsigned short* __restrict__ Ab, const unsigned short* __restrict__ Bb,
    const float* __restrict__ nf, const float* __restrict__ noise,
    const float* __restrict__ bias, const float* __restrict__ gamma,
    const float* __restrict__ beta, const float* __restrict__ bmean,
    const float* __restrict__ bvar, void* __restrict__ outp) {
  constexpr int BM = 128, BK = 64;
  constexpr int WN = MTILE / 2;
  constexpr int FJ = WN / 16;
  constexpr int NITER = K2B / BK;
  constexpr int ALD = XSTAGE ? 384 : K2A;  // agg' row is 384 ushorts

  __shared__ unsigned short sA[BM * BK];     // 16 KB
  __shared__ unsigned short sB[MTILE * BK];  // 16/8 KB

  const int tid = threadIdx.x;
  const int wid = tid >> 6;
  const int lane = tid & 63;
  const int rowbase = blockIdx.x * BM;
  const int colbase = blockIdx.y * MTILE;
  const int wr = wid >> 1, wc = wid & 1;

  f32x4 acc[4][FJ];
#pragma unroll
  for (int i = 0; i < 4; ++i)
#pragma unroll
    for (int j = 0; j < FJ; ++j) acc[i][j] = (f32x4)0.f;

  for (int kt = 0; kt < NITER; ++kt) {
    const int k0 = kt * BK;
    const int akt = (k0 < K2A) ? k0 : k0 - K2A;
    __syncthreads();

    // ---- stage A tile (128 rows x 64 cols bf16) ----
    bool gloadA = true;
    int acol = akt;
    if constexpr (XSTAGE) {
      int seg = akt / 192, rem = akt % 192;        // 0:agg_hi 1:x_hi 2:agg_lo 3:x_lo
      if (seg == 0)      { acol = rem; }
      else if (seg == 2) { acol = 192 + rem; }
      else {
        gloadA = false;
        const int ch0 = rem;         // 64 channels, never straddles nf/noise
        const bool lo = (seg == 3);
#pragma unroll
        for (int it = 0; it < 4; ++it) {
          int i = tid + it * 256;                  // 0..1023 16B slots
          int row = i >> 3, g = i & 7;
          int gr = rowbase + row; if (gr >= N_NODES) gr = N_NODES - 1;
          int ch = ch0 + g * 8;
          float4 va, vb;
          if (ch < FEAT) {
            va = ((const float4*)nf)[(size_t)gr * 32 + (ch >> 2)];
            vb = ((const float4*)nf)[(size_t)gr * 32 + (ch >> 2) + 1];
          } else {
            va = ((const float4*)noise)[(size_t)gr * 16 + ((ch - FEAT) >> 2)];
            vb = ((const float4*)noise)[(size_t)gr * 16 + ((ch - FEAT) >> 2) + 1];
          }
          float vs[8] = {va.x, va.y, va.z, va.w, vb.x, vb.y, vb.z, vb.w};
          unsigned p[4];
#pragma unroll
          for (int q = 0; q < 4; ++q) {
            unsigned short e0 = lo ? bflo(vs[2 * q])     : f2bf(vs[2 * q]);
            unsigned short e1 = lo ? bflo(vs[2 * q + 1]) : f2bf(vs[2 * q + 1]);
            p[q] = (unsigned)e0 | ((unsigned)e1 << 16);
          }
          *(uint4*)&sA[row * 64 + ((g ^ (row & 7)) * 8)] =
              make_uint4(p[0], p[1], p[2], p[3]);
        }
      }
    }
    if (gloadA) {
#pragma unroll
      for (int j = 0; j < 4; ++j) {
        int rb = j * 4 + wid;
        int row = rb * 8 + (lane >> 3);
        int slog = (lane & 7) ^ (lane >> 3);       // row&7 == lane>>3
        const char* src = (const char*)Ab +
            ((size_t)(rowbase + row) * ALD + acol) * 2 + (size_t)slog * 16;
        gload16(src, sA + rb * 512);
      }
    }

    // ---- stage B tile (MTILE cols x 64 k) ----
#pragma unroll
    for (int j = 0; j < MTILE / 32; ++j) {
      int rb = j * 4 + wid;
      int col = rb * 8 + (lane >> 3);
      int slog = (lane & 7) ^ (lane >> 3);
      const char* src = (const char*)Bb +
          ((size_t)(colbase + col) * K2B + k0) * 2 + (size_t)slog * 16;
      gload16(src, sB + rb * 512);
    }
    __syncthreads();

    // ---- compute ----
#pragma unroll
    for (int kk = 0; kk < 2; ++kk) {
      short8v a[4], b[FJ];
#pragma unroll
      for (int fi = 0; fi < 4; ++fi) {
        int rt = wr * 64 + fi * 16 + (lane & 15);
        int sl = (kk * 4 + (lane >> 4)) ^ (rt & 7);
        a[fi] = *(const short8v*)&sA[rt * 64 + sl * 8];
      }
#pragma unroll
      for (int fj = 0; fj < FJ; ++fj) {
        int ct = wc * WN + fj * 16 + (lane & 15);
        int sl = (kk * 4 + (lane >> 4)) ^ (ct & 7);
        b[fj] = *(const short8v*)&sB[ct * 64 + sl * 8];
      }
#pragma unroll
      for (int fi = 0; fi < 4; ++fi)
#pragma unroll
        for (int fj = 0; fj < FJ; ++fj)
          acc[fi][fj] = __builtin_amdgcn_mfma_f32_16x16x32_bf16(
              a[fi], b[fj], acc[fi][fj], 0, 0, 0);
    }
  }

  // ---- epilogue ----
  const int crow0 = rowbase + wr * 64;
#pragma unroll
  for (int fj = 0; fj < FJ; ++fj) {
    int gc = colbase + wc * WN + fj * 16 + (lane & 15);
    float sc, sh;
    if (OUT_MODE == 0) {
      float s = gamma[gc] * rsqrtf(bvar[gc] + BN_EPS);
      sc = s; sh = bias[gc] * s + beta[gc] - bmean[gc] * s;
    } else {
      sc = 1.f; sh = bias[gc];
    }
#pragma unroll
    for (int fi = 0; fi < 4; ++fi) {
#pragma unroll
      for (int r = 0; r < 4; ++r) {
        int gr = crow0 + fi * 16 + ((lane >> 4) << 2) + r;
        if (gr < N_NODES) {
          float v = acc[fi][fj][r] * sc + sh;
          v = (v >= 0.f) ? v : SLOPE * v;
          if (OUT_MODE == 2) {
            ((float*)outp)[(size_t)gr * MTOT + gc] = v;
          } else {
            unsigned short* o = (unsigned short*)outp + (size_t)gr * (2 * MTOT);
            o[gc] = f2bf(v);
            o[MTOT + gc] = bflo(v);
          }
        }
      }
    }
  }
}

extern "C" void kernel_launch(void* const* d_in, const int* in_sizes, int n_in,
                              void* d_out, int out_size, void* d_ws, size_t ws_size,
                              hipStream_t stream) {
  const float* nf    = (const float*)d_in[0];
  const float* noise = (const float*)d_in[1];
  const int*   ei    = (const int*)d_in[2];
  const float* Wl    = (const float*)d_in[4];
  const float* bl    = (const float*)d_in[5];
  const float* Wr    = (const float*)d_in[6];
  const float* gam   = (const float*)d_in[7];
  const float* bet   = (const float*)d_in[8];
  const float* bmean = (const float*)d_in[9];
  const float* bvar  = (const float*)d_in[10];
  const float* fc1w  = (const float*)d_in[11];
  const float* fc1b  = (const float*)d_in[12];
  const float* fc2w  = (const float*)d_in[13];
  const float* fc2b  = (const float*)d_in[14];
  const float* fc3w  = (const float*)d_in[15];
  const float* fc3b  = (const float*)d_in[16];
  const float* fc4w  = (const float*)d_in[17];
  const float* fc4b  = (const float*)d_in[18];
  float* outp = (float*)d_out;

  // ---- workspace layout (ushort units unless noted); total ~91.0 MB ----
  unsigned short* aggp = (unsigned short*)d_ws;            // [NPAD][384]
  unsigned short* hp   = aggp + (size_t)NPAD * 384;        // [NPAD][512]
  unsigned short* Wc_  = hp + (size_t)NPAD * 512;          // 256*1152
  unsigned short* W1_  = Wc_ + 256 * 1152;                 // 128*768
  unsigned short* W2_  = W1_ + 128 * 768;                  // 64*384
  unsigned short* W3_  = W2_ + 64 * 384;                   // 64*192
  unsigned short* W4_  = W3_ + 64 * 192;                   // 128*192
  int* deg    = (int*)(W4_ + 128 * 192);                   // N
  int* cursor = deg + N_NODES;                             // N
  int* bsum   = cursor + N_NODES;                          // 256
  // aliases (producers dead):
  unsigned short* h1p = aggp;                              // [NPAD][256]
  unsigned short* h2p = aggp + (size_t)NPAD * 256;         // [NPAD][128]
  unsigned short* h3p = hp;                                // [NPAD][128]
  // csr in d_out scratch (dead before fc4 writes d_out)
  int* csr = (int*)d_out;                                  // E ints = 3.2MB

  hipMemsetAsync(deg, 0, (size_t)N_NODES * sizeof(int), stream);

  wconv_kernel<<<592, 256, 0, stream>>>(Wl, Wr, fc1w, fc2w, fc3w, fc4w,
                                        Wc_, W1_, W2_, W3_, W4_);

  // --- CSR build ---
  deg_count_kernel<<<(E_EDGES + 255) / 256, 256, 0, stream>>>(ei, deg);
  block_sum_kernel<<<NB, 256, 0, stream>>>(deg, bsum);
  scan_bsum_kernel<<<1, 256, 0, stream>>>(bsum);
  scan_chunk_kernel<<<NB, 256, 0, stream>>>(deg, bsum, cursor);
  fill_kernel<<<(E_EDGES + 255) / 256, 256, 0, stream>>>(ei, cursor, csr);

  // --- Aggregate ---
  gather_kernel<<<(N_NODES + 3) / 4, 256, 0, stream>>>(
      nf, noise, csr, cursor, deg, aggp);

  const int RB = NPAD / 128;  // 391 row blocks

  // --- combine: A'=[agg_hi,x_hi | agg_lo,x_lo] (K2A=768), B'=Wc' (K2B=1152)
  gemm_split<768, 1152, 256, 128, 0, true><<<dim3(RB, 2), 256, 0, stream>>>(
      aggp, Wc_, nf, noise, bl, gam, bet, bmean, bvar, hp);
  // --- fc1: [N,512]@[768-deep] -> 128 cols
  gemm_split<512, 768, 128, 128, 1, false><<<dim3(RB, 1), 256, 0, stream>>>(
      hp, W1_, nullptr, nullptr, fc1b, nullptr, nullptr, nullptr, nullptr, h1p);
  // --- fc2 -> 64 cols
  gemm_split<256, 384, 64, 64, 1, false><<<dim3(RB, 1), 256, 0, stream>>>(
      h1p, W2_, nullptr, nullptr, fc2b, nullptr, nullptr, nullptr, nullptr, h2p);
  // --- fc3 -> 64 cols
  gemm_split<128, 192, 64, 64, 1, false><<<dim3(RB, 1), 256, 0, stream>>>(
      h2p, W3_, nullptr, nullptr, fc3b, nullptr, nullptr, nullptr, nullptr, h3p);
  // --- fc4 -> 128 cols f32 to d_out
  gemm_split<128, 192, 128, 128, 2, false><<<dim3(RB, 1), 256, 0, stream>>>(
      h3p, W4_, nullptr, nullptr, fc4b, nullptr, nullptr, nullptr, nullptr, outp);
}

// Round 4
// 287.589 us; speedup vs baseline: 3.4182x; 1.2193x over previous
//
#include <hip/hip_runtime.h>

#define N_NODES 50000
#define NPAD    50048   // 391 * 128
#define FEAT    128
#define NZ      64
#define E_EDGES 800000
#define BN_EPS  1e-5f
#define SLOPE   0.2f
#define NB      196     // ceil(N_NODES / 256)

typedef __attribute__((ext_vector_type(8))) short short8v;
typedef __attribute__((ext_vector_type(4))) float f32x4;

// ---------------- bf16 helpers (RNE) ----------------
__device__ __forceinline__ unsigned short f2bf(float v) {
  union { float f; unsigned u; } c; c.f = v;
  unsigned r = c.u + 0x7FFFu + ((c.u >> 16) & 1u);
  return (unsigned short)(r >> 16);
}
__device__ __forceinline__ float bf2f(unsigned short h) {
  union { unsigned u; float f; } c; c.u = ((unsigned)h) << 16; return c.f;
}
__device__ __forceinline__ unsigned short bflo(float v) {
  unsigned short h = f2bf(v);
  return f2bf(v - bf2f(h));
}

__device__ __forceinline__ void gload16(const void* src, const void* lds) {
  __builtin_amdgcn_global_load_lds(
      (const __attribute__((address_space(1))) unsigned int*)src,
      (__attribute__((address_space(3))) unsigned int*)lds, 16, 0, 0);
}

// ---------------------------------------------------------------------------
// CSR build (csr lives in d_out scratch; dead before fc234 writes d_out)
// ---------------------------------------------------------------------------
__global__ __launch_bounds__(256) void deg_count_kernel(
    const int* __restrict__ ei, int* __restrict__ deg) {
  int e = blockIdx.x * blockDim.x + threadIdx.x;
  if (e < E_EDGES) atomicAdd(&deg[ei[E_EDGES + e]], 1);
}

__global__ __launch_bounds__(256) void block_sum_kernel(
    const int* __restrict__ deg, int* __restrict__ bsum) {
  __shared__ int sh[256];
  int i = blockIdx.x * 256 + threadIdx.x;
  sh[threadIdx.x] = (i < N_NODES) ? deg[i] : 0;
  __syncthreads();
  for (int s = 128; s > 0; s >>= 1) {
    if (threadIdx.x < s) sh[threadIdx.x] += sh[threadIdx.x + s];
    __syncthreads();
  }
  if (threadIdx.x == 0) bsum[blockIdx.x] = sh[0];
}

__global__ __launch_bounds__(256) void scan_bsum_kernel(int* __restrict__ bsum) {
  __shared__ int sh[256];
  int t = threadIdx.x;
  sh[t] = (t < NB) ? bsum[t] : 0;
  __syncthreads();
  for (int off = 1; off < 256; off <<= 1) {
    int v = (t >= off) ? sh[t - off] : 0;
    __syncthreads();
    sh[t] += v;
    __syncthreads();
  }
  if (t < NB) bsum[t] = (t == 0) ? 0 : sh[t - 1];
}

__global__ __launch_bounds__(256) void scan_chunk_kernel(
    const int* __restrict__ deg, const int* __restrict__ bsum,
    int* __restrict__ cursor) {
  __shared__ int sh[256];
  int t = threadIdx.x;
  int i = blockIdx.x * 256 + t;
  int v = (i < N_NODES) ? deg[i] : 0;
  sh[t] = v;
  __syncthreads();
  for (int off = 1; off < 256; off <<= 1) {
    int u = (t >= off) ? sh[t - off] : 0;
    __syncthreads();
    sh[t] += u;
    __syncthreads();
  }
  if (i < N_NODES) cursor[i] = bsum[blockIdx.x] + sh[t] - v;
}

__global__ __launch_bounds__(256) void fill_kernel(
    const int* __restrict__ ei, int* __restrict__ cursor, int* __restrict__ csr) {
  int e = blockIdx.x * blockDim.x + threadIdx.x;
  if (e < E_EDGES) {
    int src = ei[e];
    int dst = ei[E_EDGES + e];
    int p = atomicAdd(&cursor[dst], 1);
    csr[p] = src;
  }
}

// ---------------------------------------------------------------------------
// Gather-aggregate: one wave per node, 4-wide unrolled; writes mean_agg as
// hi/lo bf16 blocks: agg'[n][0..191] = hi, agg'[n][192..383] = lo.
// ---------------------------------------------------------------------------
__global__ __launch_bounds__(256) void gather_kernel(
    const float* __restrict__ nf, const float* __restrict__ noise,
    const int* __restrict__ csr, const int* __restrict__ cursor,
    const int* __restrict__ deg, unsigned short* __restrict__ aggp) {
  int wid = (blockIdx.x * blockDim.x + threadIdx.x) >> 6;
  int lane = threadIdx.x & 63;
  if (wid >= N_NODES) return;
  int d = deg[wid];
  int end = cursor[wid];
  int start = end - d;

  float a0 = 0.f, a1 = 0.f, a2 = 0.f;
  float b0 = 0.f, b1 = 0.f, b2 = 0.f;
  float c0 = 0.f, c1 = 0.f, c2 = 0.f;
  float e0 = 0.f, e1 = 0.f, e2 = 0.f;
  int j = start;
  for (; j + 3 < end; j += 4) {
    int sa = csr[j], sb = csr[j + 1], sc = csr[j + 2], sd = csr[j + 3];
    a0 += nf[(size_t)sa * FEAT + lane];
    b0 += nf[(size_t)sb * FEAT + lane];
    c0 += nf[(size_t)sc * FEAT + lane];
    e0 += nf[(size_t)sd * FEAT + lane];
    a1 += nf[(size_t)sa * FEAT + 64 + lane];
    b1 += nf[(size_t)sb * FEAT + 64 + lane];
    c1 += nf[(size_t)sc * FEAT + 64 + lane];
    e1 += nf[(size_t)sd * FEAT + 64 + lane];
    a2 += noise[(size_t)sa * NZ + lane];
    b2 += noise[(size_t)sb * NZ + lane];
    c2 += noise[(size_t)sc * NZ + lane];
    e2 += noise[(size_t)sd * NZ + lane];
  }
  for (; j < end; ++j) {
    int sa = csr[j];
    a0 += nf[(size_t)sa * FEAT + lane];
    a1 += nf[(size_t)sa * FEAT + 64 + lane];
    a2 += noise[(size_t)sa * NZ + lane];
  }
  float inv = 1.0f / fmaxf((float)d, 1.0f);
  float m0 = ((a0 + b0) + (c0 + e0)) * inv;
  float m1 = ((a1 + b1) + (c1 + e1)) * inv;
  float m2 = ((a2 + b2) + (c2 + e2)) * inv;
  unsigned short* ap = aggp + (size_t)wid * 384;
  ap[lane]       = f2bf(m0);  ap[192 + lane] = bflo(m0);
  ap[64 + lane]  = f2bf(m1);  ap[256 + lane] = bflo(m1);
  ap[128 + lane] = f2bf(m2);  ap[320 + lane] = bflo(m2);
}

// ---------------------------------------------------------------------------
// Weight conversion.
// Wc' [256][768]: per col: [Wl_hi 192 | Wr_hi 192 | Wl_lo 192 | Wr_lo 192]
// W1' [128][512]: [hi 256 | lo 256]
// W2' [64][128], W3' [64][64], W4' [128][64]: plain bf16 (k-major per col).
// ---------------------------------------------------------------------------
__global__ __launch_bounds__(256) void wconv_kernel(
    const float* __restrict__ Wl, const float* __restrict__ Wr,
    const float* __restrict__ W1, const float* __restrict__ W2,
    const float* __restrict__ W3, const float* __restrict__ W4,
    unsigned short* __restrict__ Wc_, unsigned short* __restrict__ W1_,
    unsigned short* __restrict__ W2_, unsigned short* __restrict__ W3_,
    unsigned short* __restrict__ W4_) {
  int idx = blockIdx.x * 256 + threadIdx.x;
  if (idx < 49152) {                       // Wl: K=192, M=256
    int k = idx % 192, m = idx / 192;
    float v = Wl[(size_t)k * 256 + m];
    unsigned short h = f2bf(v);
    Wc_[(size_t)m * 768 + k] = h;
    Wc_[(size_t)m * 768 + 384 + k] = f2bf(v - bf2f(h));
  } else if (idx < 98304) {                // Wr: K=192, M=256
    int local = idx - 49152;
    int k = local % 192, m = local / 192;
    float v = Wr[(size_t)k * 256 + m];
    unsigned short h = f2bf(v);
    Wc_[(size_t)m * 768 + 192 + k] = h;
    Wc_[(size_t)m * 768 + 576 + k] = f2bf(v - bf2f(h));
  } else if (idx < 131072) {               // W1: K=256, M=128
    int local = idx - 98304;
    int k = local % 256, m = local / 256;
    float v = W1[(size_t)k * 128 + m];
    unsigned short h = f2bf(v);
    W1_[(size_t)m * 512 + k] = h;
    W1_[(size_t)m * 512 + 256 + k] = f2bf(v - bf2f(h));
  } else if (idx < 139264) {               // W2: K=128, M=64 (plain)
    int local = idx - 131072;
    int k = local % 128, m = local / 128;
    W2_[(size_t)m * 128 + k] = f2bf(W2[(size_t)k * 64 + m]);
  } else if (idx < 143360) {               // W3: K=64, M=64 (plain)
    int local = idx - 139264;
    int k = local % 64, m = local / 64;
    W3_[(size_t)m * 64 + k] = f2bf(W3[(size_t)k * 64 + m]);
  } else if (idx < 151552) {               // W4: K=64, M=128 (plain)
    int local = idx - 143360;
    int k = local % 64, m = local / 64;
    W4_[(size_t)m * 64 + k] = f2bf(W4[(size_t)k * 128 + m]);
  }
}

// ---------------------------------------------------------------------------
// 3-term split GEMM: acc += a_hi*w_hi + a_lo*w_hi + a_hi*w_lo.
// A rows: [hi(KA) | lo(KA)] (ALD ushorts/row); for XSTAGE base-k >= KA the
// A tile comes from nf/noise f32 with on-the-fly hi/lo split.
// B rows: [hi(KBASE) | lo(KBASE)].
// BM=128, MTILE=128, BK=64, 4 waves (2x2), 16x16x32 bf16 MFMA.
// LDS rows 128B, XOR-16B-slot swizzle; gload_lds with pre-swizzled source.
// OUT_MODE: 0 = BN+lrelu -> bf16 pair rows (2*MTOT); 1 = bias+lrelu -> bf16.
// ---------------------------------------------------------------------------
template <int KBASE, int KA, int ALD, int MTOT, int OUT_MODE, bool XSTAGE>
__global__ __launch_bounds__(256) void gemm3(
    const unsigned short* __restrict__ Ab, const unsigned short* __restrict__ Bb,
    const float* __restrict__ nf, const float* __restrict__ noise,
    const float* __restrict__ bias, const float* __restrict__ gamma,
    const float* __restrict__ beta, const float* __restrict__ bmean,
    const float* __restrict__ bvar, void* __restrict__ outp) {
  constexpr int BM = 128, MTILE = 128, BK = 64;
  constexpr int NITER = KBASE / BK;
  constexpr int BLD = 2 * KBASE;

  __shared__ unsigned short sAh[BM * BK], sAl[BM * BK];
  __shared__ unsigned short sBh[MTILE * BK], sBl[MTILE * BK];

  const int tid = threadIdx.x;
  const int wid = tid >> 6;
  const int lane = tid & 63;
  const int rowbase = blockIdx.x * BM;
  const int colbase = blockIdx.y * MTILE;
  const int wr = wid >> 1, wc = wid & 1;

  f32x4 acc[4][4];
#pragma unroll
  for (int i = 0; i < 4; ++i)
#pragma unroll
    for (int j = 0; j < 4; ++j) acc[i][j] = (f32x4)0.f;

  for (int kt = 0; kt < NITER; ++kt) {
    const int kb = kt * BK;
    __syncthreads();

    // ---- stage B hi/lo tiles ----
#pragma unroll
    for (int j = 0; j < 4; ++j) {
      int rb = j * 4 + wid;
      int row = rb * 8 + (lane >> 3);
      int slog = (lane & 7) ^ (lane >> 3);
      const char* sh = (const char*)Bb +
          ((size_t)(colbase + row) * BLD + kb) * 2 + (size_t)slog * 16;
      gload16(sh, sBh + rb * 512);
      const char* sl = (const char*)Bb +
          ((size_t)(colbase + row) * BLD + KBASE + kb) * 2 + (size_t)slog * 16;
      gload16(sl, sBl + rb * 512);
    }

    // ---- stage A hi/lo tiles ----
    if (!XSTAGE || kb < KA) {
#pragma unroll
      for (int j = 0; j < 4; ++j) {
        int rb = j * 4 + wid;
        int row = rb * 8 + (lane >> 3);
        int slog = (lane & 7) ^ (lane >> 3);
        const char* sh = (const char*)Ab +
            ((size_t)(rowbase + row) * ALD + kb) * 2 + (size_t)slog * 16;
        gload16(sh, sAh + rb * 512);
        const char* sl = (const char*)Ab +
            ((size_t)(rowbase + row) * ALD + KA + kb) * 2 + (size_t)slog * 16;
        gload16(sl, sAl + rb * 512);
      }
    } else {
      const int ch0 = kb - KA;  // 0, 64, 128: never straddles nf/noise
#pragma unroll
      for (int it = 0; it < 4; ++it) {
        int i = tid + it * 256;              // 1024 slots
        int row = i >> 3, g = i & 7;
        int gr = rowbase + row; if (gr >= N_NODES) gr = N_NODES - 1;
        int ch = ch0 + g * 8;
        float4 va, vb;
        if (ch < FEAT) {
          va = ((const float4*)nf)[(size_t)gr * 32 + (ch >> 2)];
          vb = ((const float4*)nf)[(size_t)gr * 32 + (ch >> 2) + 1];
        } else {
          va = ((const float4*)noise)[(size_t)gr * 16 + ((ch - FEAT) >> 2)];
          vb = ((const float4*)noise)[(size_t)gr * 16 + ((ch - FEAT) >> 2) + 1];
        }
        float vs[8] = {va.x, va.y, va.z, va.w, vb.x, vb.y, vb.z, vb.w};
        unsigned ph[4], pl[4];
#pragma unroll
        for (int q = 0; q < 4; ++q) {
          unsigned short h0 = f2bf(vs[2 * q]), h1 = f2bf(vs[2 * q + 1]);
          unsigned short l0 = f2bf(vs[2 * q] - bf2f(h0));
          unsigned short l1 = f2bf(vs[2 * q + 1] - bf2f(h1));
          ph[q] = (unsigned)h0 | ((unsigned)h1 << 16);
          pl[q] = (unsigned)l0 | ((unsigned)l1 << 16);
        }
        int ps = (g ^ (row & 7)) * 8;
        *(uint4*)&sAh[row * 64 + ps] = make_uint4(ph[0], ph[1], ph[2], ph[3]);
        *(uint4*)&sAl[row * 64 + ps] = make_uint4(pl[0], pl[1], pl[2], pl[3]);
      }
    }
    __syncthreads();

    // ---- compute: 3 terms ----
#pragma unroll
    for (int kk = 0; kk < 2; ++kk) {
      short8v ah[4], al[4], bt[4];
#pragma unroll
      for (int fi = 0; fi < 4; ++fi) {
        int rt = wr * 64 + fi * 16 + (lane & 15);
        int sl = (kk * 4 + (lane >> 4)) ^ (rt & 7);
        ah[fi] = *(const short8v*)&sAh[rt * 64 + sl * 8];
        al[fi] = *(const short8v*)&sAl[rt * 64 + sl * 8];
      }
#pragma unroll
      for (int fj = 0; fj < 4; ++fj) {
        int ct = wc * 64 + fj * 16 + (lane & 15);
        int sl = (kk * 4 + (lane >> 4)) ^ (ct & 7);
        bt[fj] = *(const short8v*)&sBh[ct * 64 + sl * 8];
      }
#pragma unroll
      for (int fi = 0; fi < 4; ++fi)
#pragma unroll
        for (int fj = 0; fj < 4; ++fj) {
          acc[fi][fj] = __builtin_amdgcn_mfma_f32_16x16x32_bf16(
              ah[fi], bt[fj], acc[fi][fj], 0, 0, 0);
          acc[fi][fj] = __builtin_amdgcn_mfma_f32_16x16x32_bf16(
              al[fi], bt[fj], acc[fi][fj], 0, 0, 0);
        }
#pragma unroll
      for (int fj = 0; fj < 4; ++fj) {
        int ct = wc * 64 + fj * 16 + (lane & 15);
        int sl = (kk * 4 + (lane >> 4)) ^ (ct & 7);
        bt[fj] = *(const short8v*)&sBl[ct * 64 + sl * 8];
      }
#pragma unroll
      for (int fi = 0; fi < 4; ++fi)
#pragma unroll
        for (int fj = 0; fj < 4; ++fj)
          acc[fi][fj] = __builtin_amdgcn_mfma_f32_16x16x32_bf16(
              ah[fi], bt[fj], acc[fi][fj], 0, 0, 0);
    }
  }

  // ---- epilogue ----
  const int crow0 = rowbase + wr * 64;
#pragma unroll
  for (int fj = 0; fj < 4; ++fj) {
    int gc = colbase + wc * 64 + fj * 16 + (lane & 15);
    float sc, sh;
    if (OUT_MODE == 0) {
      float s = gamma[gc] * rsqrtf(bvar[gc] + BN_EPS);
      sc = s; sh = bias[gc] * s + beta[gc] - bmean[gc] * s;
    } else {
      sc = 1.f; sh = bias[gc];
    }
#pragma unroll
    for (int fi = 0; fi < 4; ++fi) {
#pragma unroll
      for (int r = 0; r < 4; ++r) {
        int gr = crow0 + fi * 16 + ((lane >> 4) << 2) + r;
        if (gr < N_NODES) {
          float v = acc[fi][fj][r] * sc + sh;
          v = (v >= 0.f) ? v : SLOPE * v;
          if (OUT_MODE == 0) {
            unsigned short* o = (unsigned short*)outp + (size_t)gr * (2 * MTOT);
            o[gc] = f2bf(v);
            o[MTOT + gc] = bflo(v);
          } else {
            ((unsigned short*)outp)[(size_t)gr * MTOT + gc] = f2bf(v);
          }
        }
      }
    }
  }
}

// ---------------------------------------------------------------------------
// Fused fc2+fc3+fc4 (plain bf16): per 128-row block, h1 tile staged once;
// h2, h3 live only in LDS (XOR-swizzled); weights staged per phase.
// LDS map (ushort units): SA [0,16384) = h1 tile [128][128], reused as
// SH3 [128][64]; SB [16384,24576); SH2 [24576,32768) = [128][64].
// ---------------------------------------------------------------------------
__global__ __launch_bounds__(256) void fc234_kernel(
    const unsigned short* __restrict__ h1p,
    const unsigned short* __restrict__ W2_, const unsigned short* __restrict__ W3_,
    const unsigned short* __restrict__ W4_,
    const float* __restrict__ b2, const float* __restrict__ b3,
    const float* __restrict__ b4, float* __restrict__ outp) {
  __shared__ unsigned short lds[32768];
  unsigned short* SA  = lds;
  unsigned short* SB  = lds + 16384;
  unsigned short* SH2 = lds + 24576;

  const int tid = threadIdx.x;
  const int wid = tid >> 6;
  const int lane = tid & 63;
  const int rowbase = blockIdx.x * 128;
  const int wr = wid >> 1, wc = wid & 1;

  // ---- stage h1 tile [128][128] (rows 256B: 4 rows per wave-op) ----
#pragma unroll
  for (int j = 0; j < 8; ++j) {
    int o = j * 4 + wid;
    int rloc = o * 4 + (lane >> 4);
    int slog = (lane & 15) ^ ((rloc & 7) << 1);
    const char* src = (const char*)h1p +
        ((size_t)(rowbase + rloc) * 128) * 2 + (size_t)slog * 16;
    gload16(src, SA + o * 512);
  }
  // ---- stage W2' [64][128] ----
#pragma unroll
  for (int j = 0; j < 4; ++j) {
    int o = j * 4 + wid;
    int rloc = o * 4 + (lane >> 4);
    int slog = (lane & 15) ^ ((rloc & 7) << 1);
    const char* src = (const char*)W2_ +
        ((size_t)rloc * 128) * 2 + (size_t)slog * 16;
    gload16(src, SB + o * 512);
  }
  __syncthreads();

  // ---- fc2: [128x128] @ -> 64 cols ----
  f32x4 acc2[4][2];
#pragma unroll
  for (int i = 0; i < 4; ++i) { acc2[i][0] = (f32x4)0.f; acc2[i][1] = (f32x4)0.f; }
#pragma unroll
  for (int kk = 0; kk < 4; ++kk) {
    short8v a[4], b[2];
#pragma unroll
    for (int fi = 0; fi < 4; ++fi) {
      int rt = wr * 64 + fi * 16 + (lane & 15);
      int ph = (kk * 4 + (lane >> 4)) ^ ((rt & 7) << 1);
      a[fi] = *(const short8v*)&SA[rt * 128 + ph * 8];
    }
#pragma unroll
    for (int fj = 0; fj < 2; ++fj) {
      int ct = wc * 32 + fj * 16 + (lane & 15);
      int ph = (kk * 4 + (lane >> 4)) ^ ((ct & 7) << 1);
      b[fj] = *(const short8v*)&SB[ct * 128 + ph * 8];
    }
#pragma unroll
    for (int fi = 0; fi < 4; ++fi)
#pragma unroll
      for (int fj = 0; fj < 2; ++fj)
        acc2[fi][fj] = __builtin_amdgcn_mfma_f32_16x16x32_bf16(
            a[fi], b[fj], acc2[fi][fj], 0, 0, 0);
  }
  __syncthreads();

  // ---- fc2 epilogue -> SH2 [128][64]; stage W3' [64][64] ----
#pragma unroll
  for (int fj = 0; fj < 2; ++fj) {
    int gc = wc * 32 + fj * 16 + (lane & 15);
    float bb = b2[gc];
#pragma unroll
    for (int fi = 0; fi < 4; ++fi)
#pragma unroll
      for (int r = 0; r < 4; ++r) {
        int rt = wr * 64 + fi * 16 + ((lane >> 4) << 2) + r;
        float v = acc2[fi][fj][r] + bb;
        v = (v >= 0.f) ? v : SLOPE * v;
        SH2[rt * 64 + ((gc >> 3) ^ (rt & 7)) * 8 + (gc & 7)] = f2bf(v);
      }
  }
#pragma unroll
  for (int j = 0; j < 2; ++j) {
    int o = j * 4 + wid;
    int rloc = o * 8 + (lane >> 3);
    int slog = (lane & 7) ^ (lane >> 3);
    const char* src = (const char*)W3_ +
        ((size_t)rloc * 64) * 2 + (size_t)slog * 16;
    gload16(src, SB + o * 512);
  }
  __syncthreads();

  // ---- fc3: -> 64 cols ----
  f32x4 acc3[4][2];
#pragma unroll
  for (int i = 0; i < 4; ++i) { acc3[i][0] = (f32x4)0.f; acc3[i][1] = (f32x4)0.f; }
#pragma unroll
  for (int kk = 0; kk < 2; ++kk) {
    short8v a[4], b[2];
#pragma unroll
    for (int fi = 0; fi < 4; ++fi) {
      int rt = wr * 64 + fi * 16 + (lane & 15);
      int ph = (kk * 4 + (lane >> 4)) ^ (rt & 7);
      a[fi] = *(const short8v*)&SH2[rt * 64 + ph * 8];
    }
#pragma unroll
    for (int fj = 0; fj < 2; ++fj) {
      int ct = wc * 32 + fj * 16 + (lane & 15);
      int ph = (kk * 4 + (lane >> 4)) ^ (ct & 7);
      b[fj] = *(const short8v*)&SB[ct * 64 + ph * 8];
    }
#pragma unroll
    for (int fi = 0; fi < 4; ++fi)
#pragma unroll
      for (int fj = 0; fj < 2; ++fj)
        acc3[fi][fj] = __builtin_amdgcn_mfma_f32_16x16x32_bf16(
            a[fi], b[fj], acc3[fi][fj], 0, 0, 0);
  }
  __syncthreads();

  // ---- fc3 epilogue -> SH3 (over SA region); stage W4' [128][64] ----
  unsigned short* SH3 = SA;
#pragma unroll
  for (int fj = 0; fj < 2; ++fj) {
    int gc = wc * 32 + fj * 16 + (lane & 15);
    float bb = b3[gc];
#pragma unroll
    for (int fi = 0; fi < 4; ++fi)
#pragma unroll
      for (int r = 0; r < 4; ++r) {
        int rt = wr * 64 + fi * 16 + ((lane >> 4) << 2) + r;
        float v = acc3[fi][fj][r] + bb;
        v = (v >= 0.f) ? v : SLOPE * v;
        SH3[rt * 64 + ((gc >> 3) ^ (rt & 7)) * 8 + (gc & 7)] = f2bf(v);
      }
  }
#pragma unroll
  for (int j = 0; j < 4; ++j) {
    int o = j * 4 + wid;
    int rloc = o * 8 + (lane >> 3);
    int slog = (lane & 7) ^ (lane >> 3);
    const char* src = (const char*)W4_ +
        ((size_t)rloc * 64) * 2 + (size_t)slog * 16;
    gload16(src, SB + o * 512);
  }
  __syncthreads();

  // ---- fc4: -> 128 cols, f32 out ----
  f32x4 acc4[4][4];
#pragma unroll
  for (int i = 0; i < 4; ++i)
#pragma unroll
    for (int j = 0; j < 4; ++j) acc4[i][j] = (f32x4)0.f;
#pragma unroll
  for (int kk = 0; kk < 2; ++kk) {
    short8v a[4], b[4];
#pragma unroll
    for (int fi = 0; fi < 4; ++fi) {
      int rt = wr * 64 + fi * 16 + (lane & 15);
      int ph = (kk * 4 + (lane >> 4)) ^ (rt & 7);
      a[fi] = *(const short8v*)&SH3[rt * 64 + ph * 8];
    }
#pragma unroll
    for (int fj = 0; fj < 4; ++fj) {
      int ct = wc * 64 + fj * 16 + (lane & 15);
      int ph = (kk * 4 + (lane >> 4)) ^ (ct & 7);
      b[fj] = *(const short8v*)&SB[ct * 64 + ph * 8];
    }
#pragma unroll
    for (int fi = 0; fi < 4; ++fi)
#pragma unroll
      for (int fj = 0; fj < 4; ++fj)
        acc4[fi][fj] = __builtin_amdgcn_mfma_f32_16x16x32_bf16(
            a[fi], b[fj], acc4[fi][fj], 0, 0, 0);
  }

  const int crow0 = rowbase + wr * 64;
#pragma unroll
  for (int fj = 0; fj < 4; ++fj) {
    int gc = wc * 64 + fj * 16 + (lane & 15);
    float bb = b4[gc];
#pragma unroll
    for (int fi = 0; fi < 4; ++fi)
#pragma unroll
      for (int r = 0; r < 4; ++r) {
        int gr = crow0 + fi * 16 + ((lane >> 4) << 2) + r;
        if (gr < N_NODES) {
          float v = acc4[fi][fj][r] + bb;
          v = (v >= 0.f) ? v : SLOPE * v;
          outp[(size_t)gr * FEAT + gc] = v;
        }
      }
  }
}

extern "C" void kernel_launch(void* const* d_in, const int* in_sizes, int n_in,
                              void* d_out, int out_size, void* d_ws, size_t ws_size,
                              hipStream_t stream) {
  const float* nf    = (const float*)d_in[0];
  const float* noise = (const float*)d_in[1];
  const int*   ei    = (const int*)d_in[2];
  const float* Wl    = (const float*)d_in[4];
  const float* bl    = (const float*)d_in[5];
  const float* Wr    = (const float*)d_in[6];
  const float* gam   = (const float*)d_in[7];
  const float* bet   = (const float*)d_in[8];
  const float* bmean = (const float*)d_in[9];
  const float* bvar  = (const float*)d_in[10];
  const float* fc1w  = (const float*)d_in[11];
  const float* fc1b  = (const float*)d_in[12];
  const float* fc2w  = (const float*)d_in[13];
  const float* fc2b  = (const float*)d_in[14];
  const float* fc3w  = (const float*)d_in[15];
  const float* fc3b  = (const float*)d_in[16];
  const float* fc4w  = (const float*)d_in[17];
  const float* fc4b  = (const float*)d_in[18];
  float* outp = (float*)d_out;

  // ---- workspace (ushort units unless noted) ----
  unsigned short* aggp = (unsigned short*)d_ws;            // [NPAD][384]
  unsigned short* hp   = aggp + (size_t)NPAD * 384;        // [NPAD][512]
  unsigned short* Wc_  = hp + (size_t)NPAD * 512;          // 256*768
  unsigned short* W1_  = Wc_ + 256 * 768;                  // 128*512
  unsigned short* W2_  = W1_ + 128 * 512;                  // 64*128
  unsigned short* W3_  = W2_ + 64 * 128;                   // 64*64
  unsigned short* W4_  = W3_ + 64 * 64;                    // 128*64
  int* deg    = (int*)(W4_ + 128 * 64);                    // N
  int* cursor = deg + N_NODES;                             // N
  int* bsum   = cursor + N_NODES;                          // 256
  unsigned short* h1p = aggp;                              // [NPAD][128] (aggp dead after combine)
  int* csr = (int*)d_out;                                  // E ints (dead before fc234 writes)

  hipMemsetAsync(deg, 0, (size_t)N_NODES * sizeof(int), stream);

  wconv_kernel<<<592, 256, 0, stream>>>(Wl, Wr, fc1w, fc2w, fc3w, fc4w,
                                        Wc_, W1_, W2_, W3_, W4_);

  // --- CSR build ---
  deg_count_kernel<<<(E_EDGES + 255) / 256, 256, 0, stream>>>(ei, deg);
  block_sum_kernel<<<NB, 256, 0, stream>>>(deg, bsum);
  scan_bsum_kernel<<<1, 256, 0, stream>>>(bsum);
  scan_chunk_kernel<<<NB, 256, 0, stream>>>(deg, bsum, cursor);
  fill_kernel<<<(E_EDGES + 255) / 256, 256, 0, stream>>>(ei, cursor, csr);

  // --- Aggregate ---
  gather_kernel<<<(N_NODES + 3) / 4, 256, 0, stream>>>(
      nf, noise, csr, cursor, deg, aggp);

  const int RB = NPAD / 128;  // 391

  // --- combine: KBASE=384 (agg 192 + x 192), out 256 cols as hi/lo pairs ---
  gemm3<384, 192, 384, 256, 0, true><<<dim3(RB, 2), 256, 0, stream>>>(
      aggp, Wc_, nf, noise, bl, gam, bet, bmean, bvar, hp);
  // --- fc1: KBASE=256, out 128 cols plain bf16 ---
  gemm3<256, 256, 512, 128, 1, false><<<dim3(RB, 1), 256, 0, stream>>>(
      hp, W1_, nullptr, nullptr, fc1b, nullptr, nullptr, nullptr, nullptr, h1p);
  // --- fused fc2+fc3+fc4 -> f32 out ---
  fc234_kernel<<<RB, 256, 0, stream>>>(h1p, W2_, W3_, W4_,
                                       fc2b, fc3b, fc4b, outp);
}

// Round 5
// 242.483 us; speedup vs baseline: 4.0540x; 1.1860x over previous
//
#include <hip/hip_runtime.h>

#define N_NODES 50000
#define NPAD    50048   // 391 * 128
#define FEAT    128
#define NZ      64
#define E_EDGES 800000
#define BN_EPS  1e-5f
#define SLOPE   0.2f
#define NB      196     // ceil(N_NODES / 256)

typedef __attribute__((ext_vector_type(8))) short short8v;
typedef __attribute__((ext_vector_type(4))) float f32x4;

// ---------------- bf16 helpers (RNE) ----------------
__device__ __forceinline__ unsigned short f2bf(float v) {
  union { float f; unsigned u; } c; c.f = v;
  unsigned r = c.u + 0x7FFFu + ((c.u >> 16) & 1u);
  return (unsigned short)(r >> 16);
}

__device__ __forceinline__ void gload16(const void* src, const void* lds) {
  __builtin_amdgcn_global_load_lds(
      (const __attribute__((address_space(1))) unsigned int*)src,
      (__attribute__((address_space(3))) unsigned int*)lds, 16, 0, 0);
}

// ---------------------------------------------------------------------------
// CSR build (csr lives in d_out scratch; dead before fc234 writes d_out)
// ---------------------------------------------------------------------------
__global__ __launch_bounds__(256) void deg_count_kernel(
    const int* __restrict__ ei, int* __restrict__ deg) {
  int e = blockIdx.x * blockDim.x + threadIdx.x;
  if (e < E_EDGES) atomicAdd(&deg[ei[E_EDGES + e]], 1);
}

__global__ __launch_bounds__(256) void block_sum_kernel(
    const int* __restrict__ deg, int* __restrict__ bsum) {
  __shared__ int sh[256];
  int i = blockIdx.x * 256 + threadIdx.x;
  sh[threadIdx.x] = (i < N_NODES) ? deg[i] : 0;
  __syncthreads();
  for (int s = 128; s > 0; s >>= 1) {
    if (threadIdx.x < s) sh[threadIdx.x] += sh[threadIdx.x + s];
    __syncthreads();
  }
  if (threadIdx.x == 0) bsum[blockIdx.x] = sh[0];
}

__global__ __launch_bounds__(256) void scan_bsum_kernel(int* __restrict__ bsum) {
  __shared__ int sh[256];
  int t = threadIdx.x;
  sh[t] = (t < NB) ? bsum[t] : 0;
  __syncthreads();
  for (int off = 1; off < 256; off <<= 1) {
    int v = (t >= off) ? sh[t - off] : 0;
    __syncthreads();
    sh[t] += v;
    __syncthreads();
  }
  if (t < NB) bsum[t] = (t == 0) ? 0 : sh[t - 1];
}

__global__ __launch_bounds__(256) void scan_chunk_kernel(
    const int* __restrict__ deg, const int* __restrict__ bsum,
    int* __restrict__ cursor) {
  __shared__ int sh[256];
  int t = threadIdx.x;
  int i = blockIdx.x * 256 + t;
  int v = (i < N_NODES) ? deg[i] : 0;
  sh[t] = v;
  __syncthreads();
  for (int off = 1; off < 256; off <<= 1) {
    int u = (t >= off) ? sh[t - off] : 0;
    __syncthreads();
    sh[t] += u;
    __syncthreads();
  }
  if (i < N_NODES) cursor[i] = bsum[blockIdx.x] + sh[t] - v;
}

__global__ __launch_bounds__(256) void fill_kernel(
    const int* __restrict__ ei, int* __restrict__ cursor, int* __restrict__ csr) {
  int e = blockIdx.x * blockDim.x + threadIdx.x;
  if (e < E_EDGES) {
    int src = ei[e];
    int dst = ei[E_EDGES + e];
    int p = atomicAdd(&cursor[dst], 1);
    csr[p] = src;
  }
}

// ---------------------------------------------------------------------------
// Gather-aggregate: one wave per node, 4-wide unrolled; writes mean_agg as
// plain bf16 rows [NPAD][192].
// ---------------------------------------------------------------------------
__global__ __launch_bounds__(256) void gather_kernel(
    const float* __restrict__ nf, const float* __restrict__ noise,
    const int* __restrict__ csr, const int* __restrict__ cursor,
    const int* __restrict__ deg, unsigned short* __restrict__ aggp) {
  int wid = (blockIdx.x * blockDim.x + threadIdx.x) >> 6;
  int lane = threadIdx.x & 63;
  if (wid >= N_NODES) return;
  int d = deg[wid];
  int end = cursor[wid];
  int start = end - d;

  float a0 = 0.f, a1 = 0.f, a2 = 0.f;
  float b0 = 0.f, b1 = 0.f, b2 = 0.f;
  float c0 = 0.f, c1 = 0.f, c2 = 0.f;
  float e0 = 0.f, e1 = 0.f, e2 = 0.f;
  int j = start;
  for (; j + 3 < end; j += 4) {
    int sa = csr[j], sb = csr[j + 1], sc = csr[j + 2], sd = csr[j + 3];
    a0 += nf[(size_t)sa * FEAT + lane];
    b0 += nf[(size_t)sb * FEAT + lane];
    c0 += nf[(size_t)sc * FEAT + lane];
    e0 += nf[(size_t)sd * FEAT + lane];
    a1 += nf[(size_t)sa * FEAT + 64 + lane];
    b1 += nf[(size_t)sb * FEAT + 64 + lane];
    c1 += nf[(size_t)sc * FEAT + 64 + lane];
    e1 += nf[(size_t)sd * FEAT + 64 + lane];
    a2 += noise[(size_t)sa * NZ + lane];
    b2 += noise[(size_t)sb * NZ + lane];
    c2 += noise[(size_t)sc * NZ + lane];
    e2 += noise[(size_t)sd * NZ + lane];
  }
  for (; j < end; ++j) {
    int sa = csr[j];
    a0 += nf[(size_t)sa * FEAT + lane];
    a1 += nf[(size_t)sa * FEAT + 64 + lane];
    a2 += noise[(size_t)sa * NZ + lane];
  }
  float inv = 1.0f / fmaxf((float)d, 1.0f);
  unsigned short* ap = aggp + (size_t)wid * 192;
  ap[lane]       = f2bf(((a0 + b0) + (c0 + e0)) * inv);
  ap[64 + lane]  = f2bf(((a1 + b1) + (c1 + e1)) * inv);
  ap[128 + lane] = f2bf(((a2 + b2) + (c2 + e2)) * inv);
}

// ---------------------------------------------------------------------------
// Weight conversion (all plain bf16, k-major per output column):
// Wc' [256][384]: per col [Wl(:,m) 192 | Wr(:,m) 192]
// W1' [128][256]; W2' [64][128]; W3' [64][64]; W4' [128][64].
// ---------------------------------------------------------------------------
__global__ __launch_bounds__(256) void wconv_kernel(
    const float* __restrict__ Wl, const float* __restrict__ Wr,
    const float* __restrict__ W1, const float* __restrict__ W2,
    const float* __restrict__ W3, const float* __restrict__ W4,
    unsigned short* __restrict__ Wc_, unsigned short* __restrict__ W1_,
    unsigned short* __restrict__ W2_, unsigned short* __restrict__ W3_,
    unsigned short* __restrict__ W4_) {
  int idx = blockIdx.x * 256 + threadIdx.x;
  if (idx < 49152) {                       // Wl: K=192, M=256
    int k = idx % 192, m = idx / 192;
    Wc_[(size_t)m * 384 + k] = f2bf(Wl[(size_t)k * 256 + m]);
  } else if (idx < 98304) {                // Wr: K=192, M=256
    int local = idx - 49152;
    int k = local % 192, m = local / 192;
    Wc_[(size_t)m * 384 + 192 + k] = f2bf(Wr[(size_t)k * 256 + m]);
  } else if (idx < 131072) {               // W1: K=256, M=128
    int local = idx - 98304;
    int k = local % 256, m = local / 256;
    W1_[(size_t)m * 256 + k] = f2bf(W1[(size_t)k * 128 + m]);
  } else if (idx < 139264) {               // W2: K=128, M=64
    int local = idx - 131072;
    int k = local % 128, m = local / 128;
    W2_[(size_t)m * 128 + k] = f2bf(W2[(size_t)k * 64 + m]);
  } else if (idx < 143360) {               // W3: K=64, M=64
    int local = idx - 139264;
    int k = local % 64, m = local / 64;
    W3_[(size_t)m * 64 + k] = f2bf(W3[(size_t)k * 64 + m]);
  } else if (idx < 151552) {               // W4: K=64, M=128
    int local = idx - 143360;
    int k = local % 64, m = local / 64;
    W4_[(size_t)m * 64 + k] = f2bf(W4[(size_t)k * 128 + m]);
  }
}

// ---------------------------------------------------------------------------
// Plain bf16 MFMA GEMM. BM=128, MTILE=128, BK=64, 4 waves (2x2),
// 16x16x32 bf16 MFMA, 32 KB LDS (sA+sB), XOR-16B-slot swizzle, gload_lds
// with pre-swizzled source (rule #21). XSTAGE: A cols >= KAGG come from
// nf/noise f32 with on-the-fly bf16 conversion (reg-staged, swizzled write).
// Epilogue: repack output tile into LDS (reusing sA+sB = 32 KB), then write
// 256 B-contiguous row segments as uint4 (coalesced, no 2 B stores).
// OUT_MODE: 0 = BN+lrelu, 1 = bias+lrelu. Output bf16 rows of OUTLD.
// ---------------------------------------------------------------------------
template <int KBASE, int KAGG, int ALD, int OUTLD, int OUT_MODE, bool XSTAGE>
__global__ __launch_bounds__(256) void gemm_plain(
    const unsigned short* __restrict__ Ab, const unsigned short* __restrict__ Bb,
    const float* __restrict__ nf, const float* __restrict__ noise,
    const float* __restrict__ bias, const float* __restrict__ gamma,
    const float* __restrict__ beta, const float* __restrict__ bmean,
    const float* __restrict__ bvar, unsigned short* __restrict__ outp) {
  constexpr int BM = 128, MTILE = 128, BK = 64;
  constexpr int NITER = KBASE / BK;

  __shared__ unsigned short lds[16384];  // 32 KB
  unsigned short* sA = lds;              // [128][64]
  unsigned short* sB = lds + 8192;       // [128][64]

  const int tid = threadIdx.x;
  const int wid = tid >> 6;
  const int lane = tid & 63;
  const int rowbase = blockIdx.x * BM;
  const int colbase = blockIdx.y * MTILE;
  const int wr = wid >> 1, wc = wid & 1;

  f32x4 acc[4][4];
#pragma unroll
  for (int i = 0; i < 4; ++i)
#pragma unroll
    for (int j = 0; j < 4; ++j) acc[i][j] = (f32x4)0.f;

  for (int kt = 0; kt < NITER; ++kt) {
    const int kb = kt * BK;
    __syncthreads();

    // ---- stage B tile [128 cols][64 k] ----
#pragma unroll
    for (int j = 0; j < 4; ++j) {
      int rb = j * 4 + wid;
      int row = rb * 8 + (lane >> 3);
      int slog = (lane & 7) ^ (lane >> 3);
      const char* src = (const char*)Bb +
          ((size_t)(colbase + row) * KBASE + kb) * 2 + (size_t)slog * 16;
      gload16(src, sB + rb * 512);
    }

    // ---- stage A tile [128 rows][64 k] ----
    if (!XSTAGE || kb < KAGG) {
#pragma unroll
      for (int j = 0; j < 4; ++j) {
        int rb = j * 4 + wid;
        int row = rb * 8 + (lane >> 3);
        int slog = (lane & 7) ^ (lane >> 3);
        const char* src = (const char*)Ab +
            ((size_t)(rowbase + row) * ALD + kb) * 2 + (size_t)slog * 16;
        gload16(src, sA + rb * 512);
      }
    } else {
      const int ch0 = kb - KAGG;  // 0, 64, 128: never straddles nf/noise
#pragma unroll
      for (int it = 0; it < 4; ++it) {
        int i = tid + it * 256;              // 1024 16B-slots
        int row = i >> 3, g = i & 7;
        int gr = rowbase + row; if (gr >= N_NODES) gr = N_NODES - 1;
        int ch = ch0 + g * 8;
        float4 va, vb;
        if (ch < FEAT) {
          va = ((const float4*)nf)[(size_t)gr * 32 + (ch >> 2)];
          vb = ((const float4*)nf)[(size_t)gr * 32 + (ch >> 2) + 1];
        } else {
          va = ((const float4*)noise)[(size_t)gr * 16 + ((ch - FEAT) >> 2)];
          vb = ((const float4*)noise)[(size_t)gr * 16 + ((ch - FEAT) >> 2) + 1];
        }
        unsigned p0 = (unsigned)f2bf(va.x) | ((unsigned)f2bf(va.y) << 16);
        unsigned p1 = (unsigned)f2bf(va.z) | ((unsigned)f2bf(va.w) << 16);
        unsigned p2 = (unsigned)f2bf(vb.x) | ((unsigned)f2bf(vb.y) << 16);
        unsigned p3 = (unsigned)f2bf(vb.z) | ((unsigned)f2bf(vb.w) << 16);
        *(uint4*)&sA[row * 64 + ((g ^ (row & 7)) * 8)] = make_uint4(p0, p1, p2, p3);
      }
    }
    __syncthreads();

    // ---- compute ----
#pragma unroll
    for (int kk = 0; kk < 2; ++kk) {
      short8v a[4], b[4];
#pragma unroll
      for (int fi = 0; fi < 4; ++fi) {
        int rt = wr * 64 + fi * 16 + (lane & 15);
        int sl = (kk * 4 + (lane >> 4)) ^ (rt & 7);
        a[fi] = *(const short8v*)&sA[rt * 64 + sl * 8];
      }
#pragma unroll
      for (int fj = 0; fj < 4; ++fj) {
        int ct = wc * 64 + fj * 16 + (lane & 15);
        int sl = (kk * 4 + (lane >> 4)) ^ (ct & 7);
        b[fj] = *(const short8v*)&sB[ct * 64 + sl * 8];
      }
#pragma unroll
      for (int fi = 0; fi < 4; ++fi)
#pragma unroll
        for (int fj = 0; fj < 4; ++fj)
          acc[fi][fj] = __builtin_amdgcn_mfma_f32_16x16x32_bf16(
              a[fi], b[fj], acc[fi][fj], 0, 0, 0);
    }
  }

  // ---- epilogue: repack tile into LDS, then coalesced row writes ----
  __syncthreads();
#pragma unroll
  for (int fj = 0; fj < 4; ++fj) {
    int gcl = wc * 64 + fj * 16 + (lane & 15);
    int gc = colbase + gcl;
    float sc, sh;
    if (OUT_MODE == 0) {
      float s = gamma[gc] * rsqrtf(bvar[gc] + BN_EPS);
      sc = s; sh = bias[gc] * s + beta[gc] - bmean[gc] * s;
    } else {
      sc = 1.f; sh = bias[gc];
    }
#pragma unroll
    for (int fi = 0; fi < 4; ++fi)
#pragma unroll
      for (int r = 0; r < 4; ++r) {
        int rt = wr * 64 + fi * 16 + ((lane >> 4) << 2) + r;
        float v = acc[fi][fj][r] * sc + sh;
        v = (v >= 0.f) ? v : SLOPE * v;
        lds[rt * 128 + gcl] = f2bf(v);
      }
  }
  __syncthreads();
  // 128 rows x 16 uint4/row = 2048 uint4; 8 per thread; padding rows are
  // harmless (outp arrays are NPAD-sized workspace).
#pragma unroll
  for (int i0 = 0; i0 < 8; ++i0) {
    int i = tid + i0 * 256;
    int row = i >> 4, u4 = i & 15;
    ((uint4*)(outp + (size_t)(rowbase + row) * OUTLD + colbase))[u4] =
        ((const uint4*)lds)[i];
  }
}

// ---------------------------------------------------------------------------
// Fused fc2+fc3+fc4 (plain bf16): per 128-row block, h1 tile staged once;
// h2, h3 live only in LDS (XOR-swizzled); weights staged per phase.
// LDS map (ushort units): SA [0,16384) = h1 tile [128][128], reused as
// SH3 [128][64]; SB [16384,24576); SH2 [24576,32768) = [128][64].
// ---------------------------------------------------------------------------
__global__ __launch_bounds__(256) void fc234_kernel(
    const unsigned short* __restrict__ h1p,
    const unsigned short* __restrict__ W2_, const unsigned short* __restrict__ W3_,
    const unsigned short* __restrict__ W4_,
    const float* __restrict__ b2, const float* __restrict__ b3,
    const float* __restrict__ b4, float* __restrict__ outp) {
  __shared__ unsigned short lds[32768];
  unsigned short* SA  = lds;
  unsigned short* SB  = lds + 16384;
  unsigned short* SH2 = lds + 24576;

  const int tid = threadIdx.x;
  const int wid = tid >> 6;
  const int lane = tid & 63;
  const int rowbase = blockIdx.x * 128;
  const int wr = wid >> 1, wc = wid & 1;

  // ---- stage h1 tile [128][128] (rows 256B = 16 slots) ----
#pragma unroll
  for (int j = 0; j < 8; ++j) {
    int o = j * 4 + wid;
    int rloc = o * 4 + (lane >> 4);
    int slog = (lane & 15) ^ ((rloc & 7) << 1);
    const char* src = (const char*)h1p +
        ((size_t)(rowbase + rloc) * 128) * 2 + (size_t)slog * 16;
    gload16(src, SA + o * 512);
  }
  // ---- stage W2' [64][128] ----
#pragma unroll
  for (int j = 0; j < 4; ++j) {
    int o = j * 4 + wid;
    int rloc = o * 4 + (lane >> 4);
    int slog = (lane & 15) ^ ((rloc & 7) << 1);
    const char* src = (const char*)W2_ +
        ((size_t)rloc * 128) * 2 + (size_t)slog * 16;
    gload16(src, SB + o * 512);
  }
  __syncthreads();

  // ---- fc2: -> 64 cols ----
  f32x4 acc2[4][2];
#pragma unroll
  for (int i = 0; i < 4; ++i) { acc2[i][0] = (f32x4)0.f; acc2[i][1] = (f32x4)0.f; }
#pragma unroll
  for (int kk = 0; kk < 4; ++kk) {
    short8v a[4], b[2];
#pragma unroll
    for (int fi = 0; fi < 4; ++fi) {
      int rt = wr * 64 + fi * 16 + (lane & 15);
      int ph = (kk * 4 + (lane >> 4)) ^ ((rt & 7) << 1);
      a[fi] = *(const short8v*)&SA[rt * 128 + ph * 8];
    }
#pragma unroll
    for (int fj = 0; fj < 2; ++fj) {
      int ct = wc * 32 + fj * 16 + (lane & 15);
      int ph = (kk * 4 + (lane >> 4)) ^ ((ct & 7) << 1);
      b[fj] = *(const short8v*)&SB[ct * 128 + ph * 8];
    }
#pragma unroll
    for (int fi = 0; fi < 4; ++fi)
#pragma unroll
      for (int fj = 0; fj < 2; ++fj)
        acc2[fi][fj] = __builtin_amdgcn_mfma_f32_16x16x32_bf16(
            a[fi], b[fj], acc2[fi][fj], 0, 0, 0);
  }
  __syncthreads();

  // ---- fc2 epilogue -> SH2 [128][64]; stage W3' [64][64] ----
#pragma unroll
  for (int fj = 0; fj < 2; ++fj) {
    int gc = wc * 32 + fj * 16 + (lane & 15);
    float bb = b2[gc];
#pragma unroll
    for (int fi = 0; fi < 4; ++fi)
#pragma unroll
      for (int r = 0; r < 4; ++r) {
        int rt = wr * 64 + fi * 16 + ((lane >> 4) << 2) + r;
        float v = acc2[fi][fj][r] + bb;
        v = (v >= 0.f) ? v : SLOPE * v;
        SH2[rt * 64 + ((gc >> 3) ^ (rt & 7)) * 8 + (gc & 7)] = f2bf(v);
      }
  }
#pragma unroll
  for (int j = 0; j < 2; ++j) {
    int o = j * 4 + wid;
    int rloc = o * 8 + (lane >> 3);
    int slog = (lane & 7) ^ (lane >> 3);
    const char* src = (const char*)W3_ +
        ((size_t)rloc * 64) * 2 + (size_t)slog * 16;
    gload16(src, SB + o * 512);
  }
  __syncthreads();

  // ---- fc3: -> 64 cols ----
  f32x4 acc3[4][2];
#pragma unroll
  for (int i = 0; i < 4; ++i) { acc3[i][0] = (f32x4)0.f; acc3[i][1] = (f32x4)0.f; }
#pragma unroll
  for (int kk = 0; kk < 2; ++kk) {
    short8v a[4], b[2];
#pragma unroll
    for (int fi = 0; fi < 4; ++fi) {
      int rt = wr * 64 + fi * 16 + (lane & 15);
      int ph = (kk * 4 + (lane >> 4)) ^ (rt & 7);
      a[fi] = *(const short8v*)&SH2[rt * 64 + ph * 8];
    }
#pragma unroll
    for (int fj = 0; fj < 2; ++fj) {
      int ct = wc * 32 + fj * 16 + (lane & 15);
      int ph = (kk * 4 + (lane >> 4)) ^ (ct & 7);
      b[fj] = *(const short8v*)&SB[ct * 64 + ph * 8];
    }
#pragma unroll
    for (int fi = 0; fi < 4; ++fi)
#pragma unroll
      for (int fj = 0; fj < 2; ++fj)
        acc3[fi][fj] = __builtin_amdgcn_mfma_f32_16x16x32_bf16(
            a[fi], b[fj], acc3[fi][fj], 0, 0, 0);
  }
  __syncthreads();

  // ---- fc3 epilogue -> SH3 (over SA region); stage W4' [128][64] ----
  unsigned short* SH3 = SA;
#pragma unroll
  for (int fj = 0; fj < 2; ++fj) {
    int gc = wc * 32 + fj * 16 + (lane & 15);
    float bb = b3[gc];
#pragma unroll
    for (int fi = 0; fi < 4; ++fi)
#pragma unroll
      for (int r = 0; r < 4; ++r) {
        int rt = wr * 64 + fi * 16 + ((lane >> 4) << 2) + r;
        float v = acc3[fi][fj][r] + bb;
        v = (v >= 0.f) ? v : SLOPE * v;
        SH3[rt * 64 + ((gc >> 3) ^ (rt & 7)) * 8 + (gc & 7)] = f2bf(v);
      }
  }
#pragma unroll
  for (int j = 0; j < 4; ++j) {
    int o = j * 4 + wid;
    int rloc = o * 8 + (lane >> 3);
    int slog = (lane & 7) ^ (lane >> 3);
    const char* src = (const char*)W4_ +
        ((size_t)rloc * 64) * 2 + (size_t)slog * 16;
    gload16(src, SB + o * 512);
  }
  __syncthreads();

  // ---- fc4: -> 128 cols, f32 out ----
  f32x4 acc4[4][4];
#pragma unroll
  for (int i = 0; i < 4; ++i)
#pragma unroll
    for (int j = 0; j < 4; ++j) acc4[i][j] = (f32x4)0.f;
#pragma unroll
  for (int kk = 0; kk < 2; ++kk) {
    short8v a[4], b[4];
#pragma unroll
    for (int fi = 0; fi < 4; ++fi) {
      int rt = wr * 64 + fi * 16 + (lane & 15);
      int ph = (kk * 4 + (lane >> 4)) ^ (rt & 7);
      a[fi] = *(const short8v*)&SH3[rt * 64 + ph * 8];
    }
#pragma unroll
    for (int fj = 0; fj < 4; ++fj) {
      int ct = wc * 64 + fj * 16 + (lane & 15);
      int ph = (kk * 4 + (lane >> 4)) ^ (ct & 7);
      b[fj] = *(const short8v*)&SB[ct * 64 + ph * 8];
    }
#pragma unroll
    for (int fi = 0; fi < 4; ++fi)
#pragma unroll
      for (int fj = 0; fj < 4; ++fj)
        acc4[fi][fj] = __builtin_amdgcn_mfma_f32_16x16x32_bf16(
            a[fi], b[fj], acc4[fi][fj], 0, 0, 0);
  }

  const int crow0 = rowbase + wr * 64;
#pragma unroll
  for (int fj = 0; fj < 4; ++fj) {
    int gc = wc * 64 + fj * 16 + (lane & 15);
    float bb = b4[gc];
#pragma unroll
    for (int fi = 0; fi < 4; ++fi)
#pragma unroll
      for (int r = 0; r < 4; ++r) {
        int gr = crow0 + fi * 16 + ((lane >> 4) << 2) + r;
        if (gr < N_NODES) {
          float v = acc4[fi][fj][r] + bb;
          v = (v >= 0.f) ? v : SLOPE * v;
          outp[(size_t)gr * FEAT + gc] = v;
        }
      }
  }
}

extern "C" void kernel_launch(void* const* d_in, const int* in_sizes, int n_in,
                              void* d_out, int out_size, void* d_ws, size_t ws_size,
                              hipStream_t stream) {
  const float* nf    = (const float*)d_in[0];
  const float* noise = (const float*)d_in[1];
  const int*   ei    = (const int*)d_in[2];
  const float* Wl    = (const float*)d_in[4];
  const float* bl    = (const float*)d_in[5];
  const float* Wr    = (const float*)d_in[6];
  const float* gam   = (const float*)d_in[7];
  const float* bet   = (const float*)d_in[8];
  const float* bmean = (const float*)d_in[9];
  const float* bvar  = (const float*)d_in[10];
  const float* fc1w  = (const float*)d_in[11];
  const float* fc1b  = (const float*)d_in[12];
  const float* fc2w  = (const float*)d_in[13];
  const float* fc2b  = (const float*)d_in[14];
  const float* fc3w  = (const float*)d_in[15];
  const float* fc3b  = (const float*)d_in[16];
  const float* fc4w  = (const float*)d_in[17];
  const float* fc4b  = (const float*)d_in[18];
  float* outp = (float*)d_out;

  // ---- workspace (ushort units unless noted); total ~46 MB ----
  unsigned short* aggp = (unsigned short*)d_ws;            // [NPAD][192]
  unsigned short* hp   = aggp + (size_t)NPAD * 192;        // [NPAD][256]
  unsigned short* Wc_  = hp + (size_t)NPAD * 256;          // 256*384
  unsigned short* W1_  = Wc_ + 256 * 384;                  // 128*256
  unsigned short* W2_  = W1_ + 128 * 256;                  // 64*128
  unsigned short* W3_  = W2_ + 64 * 128;                   // 64*64
  unsigned short* W4_  = W3_ + 64 * 64;                    // 128*64
  int* deg    = (int*)(W4_ + 128 * 64);                    // N
  int* cursor = deg + N_NODES;                             // N
  int* bsum   = cursor + N_NODES;                          // 256
  unsigned short* h1p = aggp;                              // [NPAD][128] (aggp dead after combine)
  int* csr = (int*)d_out;                                  // E ints (dead before fc234 writes)

  hipMemsetAsync(deg, 0, (size_t)N_NODES * sizeof(int), stream);

  wconv_kernel<<<592, 256, 0, stream>>>(Wl, Wr, fc1w, fc2w, fc3w, fc4w,
                                        Wc_, W1_, W2_, W3_, W4_);

  // --- CSR build ---
  deg_count_kernel<<<(E_EDGES + 255) / 256, 256, 0, stream>>>(ei, deg);
  block_sum_kernel<<<NB, 256, 0, stream>>>(deg, bsum);
  scan_bsum_kernel<<<1, 256, 0, stream>>>(bsum);
  scan_chunk_kernel<<<NB, 256, 0, stream>>>(deg, bsum, cursor);
  fill_kernel<<<(E_EDGES + 255) / 256, 256, 0, stream>>>(ei, cursor, csr);

  // --- Aggregate ---
  gather_kernel<<<(N_NODES + 3) / 4, 256, 0, stream>>>(
      nf, noise, csr, cursor, deg, aggp);

  const int RB = NPAD / 128;  // 391

  // --- combine: K=384 ([agg 192 | x 192]), out 256 cols bf16 + BN+lrelu ---
  gemm_plain<384, 192, 192, 256, 0, true><<<dim3(RB, 2), 256, 0, stream>>>(
      aggp, Wc_, nf, noise, bl, gam, bet, bmean, bvar, hp);
  // --- fc1: K=256, out 128 cols bf16 + bias+lrelu ---
  gemm_plain<256, 256, 256, 128, 1, false><<<dim3(RB, 1), 256, 0, stream>>>(
      hp, W1_, nullptr, nullptr, fc1b, nullptr, nullptr, nullptr, nullptr, h1p);
  // --- fused fc2+fc3+fc4 -> f32 out ---
  fc234_kernel<<<RB, 256, 0, stream>>>(h1p, W2_, W3_, W4_,
                                       fc2b, fc3b, fc4b, outp);
}

// Round 6
// 209.079 us; speedup vs baseline: 4.7017x; 1.1598x over previous
//
#include <hip/hip_runtime.h>

#define N_NODES 50000
#define NPAD    50048   // 391 * 128
#define FEAT    128
#define NZ      64
#define E_EDGES 800000
#define BN_EPS  1e-5f
#define SLOPE   0.2f
#define NB      196     // ceil(N_NODES / 256)

typedef __attribute__((ext_vector_type(8))) short short8v;
typedef __attribute__((ext_vector_type(4))) float f32x4;

// ---------------- bf16 helpers (RNE) ----------------
__device__ __forceinline__ unsigned short f2bf(float v) {
  union { float f; unsigned u; } c; c.f = v;
  unsigned r = c.u + 0x7FFFu + ((c.u >> 16) & 1u);
  return (unsigned short)(r >> 16);
}
__device__ __forceinline__ float bf2f(unsigned short h) {
  union { unsigned u; float f; } c; c.u = ((unsigned)h) << 16; return c.f;
}

__device__ __forceinline__ void gload16(const void* src, const void* lds) {
  __builtin_amdgcn_global_load_lds(
      (const __attribute__((address_space(1))) unsigned int*)src,
      (__attribute__((address_space(3))) unsigned int*)lds, 16, 0, 0);
}

// ---------------------------------------------------------------------------
// x-table conversion: nf/noise f32 -> xa[n][192..384) bf16.
// One 8-channel slot per thread (24 slots/node).
// ---------------------------------------------------------------------------
__global__ __launch_bounds__(256) void xconv_kernel(
    const float* __restrict__ nf, const float* __restrict__ noise,
    unsigned short* __restrict__ xa) {
  int i = blockIdx.x * 256 + threadIdx.x;
  if (i >= N_NODES * 24) return;
  int n = i / 24, s = i % 24;
  float4 va, vb;
  if (s < 16) {
    va = ((const float4*)nf)[(size_t)n * 32 + s * 2];
    vb = ((const float4*)nf)[(size_t)n * 32 + s * 2 + 1];
  } else {
    int t = s - 16;
    va = ((const float4*)noise)[(size_t)n * 16 + t * 2];
    vb = ((const float4*)noise)[(size_t)n * 16 + t * 2 + 1];
  }
  unsigned p0 = (unsigned)f2bf(va.x) | ((unsigned)f2bf(va.y) << 16);
  unsigned p1 = (unsigned)f2bf(va.z) | ((unsigned)f2bf(va.w) << 16);
  unsigned p2 = (unsigned)f2bf(vb.x) | ((unsigned)f2bf(vb.y) << 16);
  unsigned p3 = (unsigned)f2bf(vb.z) | ((unsigned)f2bf(vb.w) << 16);
  *(uint4*)&xa[(size_t)n * 384 + 192 + s * 8] = make_uint4(p0, p1, p2, p3);
}

// ---------------------------------------------------------------------------
// CSR build (csr lives in d_out scratch; dead before fc234 writes d_out)
// ---------------------------------------------------------------------------
__global__ __launch_bounds__(256) void deg_count_kernel(
    const int* __restrict__ ei, int* __restrict__ deg) {
  int e = blockIdx.x * blockDim.x + threadIdx.x;
  if (e < E_EDGES) atomicAdd(&deg[ei[E_EDGES + e]], 1);
}

__global__ __launch_bounds__(256) void block_sum_kernel(
    const int* __restrict__ deg, int* __restrict__ bsum) {
  __shared__ int sh[256];
  int i = blockIdx.x * 256 + threadIdx.x;
  sh[threadIdx.x] = (i < N_NODES) ? deg[i] : 0;
  __syncthreads();
  for (int s = 128; s > 0; s >>= 1) {
    if (threadIdx.x < s) sh[threadIdx.x] += sh[threadIdx.x + s];
    __syncthreads();
  }
  if (threadIdx.x == 0) bsum[blockIdx.x] = sh[0];
}

__global__ __launch_bounds__(256) void scan_bsum_kernel(int* __restrict__ bsum) {
  __shared__ int sh[256];
  int t = threadIdx.x;
  sh[t] = (t < NB) ? bsum[t] : 0;
  __syncthreads();
  for (int off = 1; off < 256; off <<= 1) {
    int v = (t >= off) ? sh[t - off] : 0;
    __syncthreads();
    sh[t] += v;
    __syncthreads();
  }
  if (t < NB) bsum[t] = (t == 0) ? 0 : sh[t - 1];
}

__global__ __launch_bounds__(256) void scan_chunk_kernel(
    const int* __restrict__ deg, const int* __restrict__ bsum,
    int* __restrict__ cursor) {
  __shared__ int sh[256];
  int t = threadIdx.x;
  int i = blockIdx.x * 256 + t;
  int v = (i < N_NODES) ? deg[i] : 0;
  sh[t] = v;
  __syncthreads();
  for (int off = 1; off < 256; off <<= 1) {
    int u = (t >= off) ? sh[t - off] : 0;
    __syncthreads();
    sh[t] += u;
    __syncthreads();
  }
  if (i < N_NODES) cursor[i] = bsum[blockIdx.x] + sh[t] - v;
}

__global__ __launch_bounds__(256) void fill_kernel(
    const int* __restrict__ ei, int* __restrict__ cursor, int* __restrict__ csr) {
  int e = blockIdx.x * blockDim.x + threadIdx.x;
  if (e < E_EDGES) {
    int src = ei[e];
    int dst = ei[E_EDGES + e];
    int p = atomicAdd(&cursor[dst], 1);
    csr[p] = src;
  }
}

// ---------------------------------------------------------------------------
// Gather-aggregate (bf16 source): one wave per node, 4-wide unrolled.
// Reads neighbor x rows from xa cols [192,384), f32-accumulates, writes
// mean_agg bf16 into own row cols [0,192).
// ---------------------------------------------------------------------------
__global__ __launch_bounds__(256) void gather_kernel(
    const int* __restrict__ csr, const int* __restrict__ cursor,
    const int* __restrict__ deg, unsigned short* __restrict__ xa) {
  int wid = (blockIdx.x * blockDim.x + threadIdx.x) >> 6;
  int lane = threadIdx.x & 63;
  if (wid >= N_NODES) return;
  int d = deg[wid];
  int end = cursor[wid];
  int start = end - d;

  float a0 = 0.f, a1 = 0.f, a2 = 0.f;
  float b0 = 0.f, b1 = 0.f, b2 = 0.f;
  float c0 = 0.f, c1 = 0.f, c2 = 0.f;
  float e0 = 0.f, e1 = 0.f, e2 = 0.f;
  int j = start;
  for (; j + 3 < end; j += 4) {
    const unsigned short* ra = xa + (size_t)csr[j] * 384 + 192;
    const unsigned short* rb = xa + (size_t)csr[j + 1] * 384 + 192;
    const unsigned short* rc = xa + (size_t)csr[j + 2] * 384 + 192;
    const unsigned short* re = xa + (size_t)csr[j + 3] * 384 + 192;
    a0 += bf2f(ra[lane]);       b0 += bf2f(rb[lane]);
    c0 += bf2f(rc[lane]);       e0 += bf2f(re[lane]);
    a1 += bf2f(ra[64 + lane]);  b1 += bf2f(rb[64 + lane]);
    c1 += bf2f(rc[64 + lane]);  e1 += bf2f(re[64 + lane]);
    a2 += bf2f(ra[128 + lane]); b2 += bf2f(rb[128 + lane]);
    c2 += bf2f(rc[128 + lane]); e2 += bf2f(re[128 + lane]);
  }
  for (; j < end; ++j) {
    const unsigned short* ra = xa + (size_t)csr[j] * 384 + 192;
    a0 += bf2f(ra[lane]);
    a1 += bf2f(ra[64 + lane]);
    a2 += bf2f(ra[128 + lane]);
  }
  float inv = 1.0f / fmaxf((float)d, 1.0f);
  unsigned short* ap = xa + (size_t)wid * 384;
  ap[lane]       = f2bf(((a0 + b0) + (c0 + e0)) * inv);
  ap[64 + lane]  = f2bf(((a1 + b1) + (c1 + e1)) * inv);
  ap[128 + lane] = f2bf(((a2 + b2) + (c2 + e2)) * inv);
}

// ---------------------------------------------------------------------------
// Weight conversion (all plain bf16, k-major per output column):
// Wc' [256][384]: per col [Wl(:,m) 192 | Wr(:,m) 192]
// W1' [128][256]; W2' [64][128]; W3' [64][64]; W4' [128][64].
// ---------------------------------------------------------------------------
__global__ __launch_bounds__(256) void wconv_kernel(
    const float* __restrict__ Wl, const float* __restrict__ Wr,
    const float* __restrict__ W1, const float* __restrict__ W2,
    const float* __restrict__ W3, const float* __restrict__ W4,
    unsigned short* __restrict__ Wc_, unsigned short* __restrict__ W1_,
    unsigned short* __restrict__ W2_, unsigned short* __restrict__ W3_,
    unsigned short* __restrict__ W4_) {
  int idx = blockIdx.x * 256 + threadIdx.x;
  if (idx < 49152) {                       // Wl: K=192, M=256
    int k = idx % 192, m = idx / 192;
    Wc_[(size_t)m * 384 + k] = f2bf(Wl[(size_t)k * 256 + m]);
  } else if (idx < 98304) {                // Wr: K=192, M=256
    int local = idx - 49152;
    int k = local % 192, m = local / 192;
    Wc_[(size_t)m * 384 + 192 + k] = f2bf(Wr[(size_t)k * 256 + m]);
  } else if (idx < 131072) {               // W1: K=256, M=128
    int local = idx - 98304;
    int k = local % 256, m = local / 256;
    W1_[(size_t)m * 256 + k] = f2bf(W1[(size_t)k * 128 + m]);
  } else if (idx < 139264) {               // W2: K=128, M=64
    int local = idx - 131072;
    int k = local % 128, m = local / 128;
    W2_[(size_t)m * 128 + k] = f2bf(W2[(size_t)k * 64 + m]);
  } else if (idx < 143360) {               // W3: K=64, M=64
    int local = idx - 139264;
    int k = local % 64, m = local / 64;
    W3_[(size_t)m * 64 + k] = f2bf(W3[(size_t)k * 64 + m]);
  } else if (idx < 151552) {               // W4: K=64, M=128
    int local = idx - 143360;
    int k = local % 64, m = local / 64;
    W4_[(size_t)m * 64 + k] = f2bf(W4[(size_t)k * 128 + m]);
  }
}

// ---------------------------------------------------------------------------
// Plain bf16 MFMA GEMM. BM=128, MTILE=128, BK=64, 4 waves (2x2),
// 16x16x32 bf16 MFMA, 32 KB LDS, XOR-16B-slot swizzle, all staging via
// global_load_lds with pre-swizzled source (rule #21).
// Epilogue: repack output tile into LDS, then coalesced uint4 row writes.
// OUT_MODE: 0 = BN+lrelu, 1 = bias+lrelu. Output bf16 rows of OUTLD.
// ---------------------------------------------------------------------------
template <int KBASE, int ALD, int OUTLD, int OUT_MODE>
__global__ __launch_bounds__(256) void gemm_plain(
    const unsigned short* __restrict__ Ab, const unsigned short* __restrict__ Bb,
    const float* __restrict__ bias, const float* __restrict__ gamma,
    const float* __restrict__ beta, const float* __restrict__ bmean,
    const float* __restrict__ bvar, unsigned short* __restrict__ outp) {
  constexpr int BM = 128, MTILE = 128, BK = 64;
  constexpr int NITER = KBASE / BK;

  __shared__ unsigned short lds[16384];  // 32 KB
  unsigned short* sA = lds;              // [128][64]
  unsigned short* sB = lds + 8192;       // [128][64]

  const int tid = threadIdx.x;
  const int wid = tid >> 6;
  const int lane = tid & 63;
  const int rowbase = blockIdx.x * BM;
  const int colbase = blockIdx.y * MTILE;
  const int wr = wid >> 1, wc = wid & 1;

  f32x4 acc[4][4];
#pragma unroll
  for (int i = 0; i < 4; ++i)
#pragma unroll
    for (int j = 0; j < 4; ++j) acc[i][j] = (f32x4)0.f;

  for (int kt = 0; kt < NITER; ++kt) {
    const int kb = kt * BK;
    __syncthreads();

    // ---- stage B tile [128 cols][64 k] ----
#pragma unroll
    for (int j = 0; j < 4; ++j) {
      int rb = j * 4 + wid;
      int row = rb * 8 + (lane >> 3);
      int slog = (lane & 7) ^ (lane >> 3);
      const char* src = (const char*)Bb +
          ((size_t)(colbase + row) * KBASE + kb) * 2 + (size_t)slog * 16;
      gload16(src, sB + rb * 512);
    }
    // ---- stage A tile [128 rows][64 k] ----
#pragma unroll
    for (int j = 0; j < 4; ++j) {
      int rb = j * 4 + wid;
      int row = rb * 8 + (lane >> 3);
      int slog = (lane & 7) ^ (lane >> 3);
      const char* src = (const char*)Ab +
          ((size_t)(rowbase + row) * ALD + kb) * 2 + (size_t)slog * 16;
      gload16(src, sA + rb * 512);
    }
    __syncthreads();

    // ---- compute ----
#pragma unroll
    for (int kk = 0; kk < 2; ++kk) {
      short8v a[4], b[4];
#pragma unroll
      for (int fi = 0; fi < 4; ++fi) {
        int rt = wr * 64 + fi * 16 + (lane & 15);
        int sl = (kk * 4 + (lane >> 4)) ^ (rt & 7);
        a[fi] = *(const short8v*)&sA[rt * 64 + sl * 8];
      }
#pragma unroll
      for (int fj = 0; fj < 4; ++fj) {
        int ct = wc * 64 + fj * 16 + (lane & 15);
        int sl = (kk * 4 + (lane >> 4)) ^ (ct & 7);
        b[fj] = *(const short8v*)&sB[ct * 64 + sl * 8];
      }
#pragma unroll
      for (int fi = 0; fi < 4; ++fi)
#pragma unroll
        for (int fj = 0; fj < 4; ++fj)
          acc[fi][fj] = __builtin_amdgcn_mfma_f32_16x16x32_bf16(
              a[fi], b[fj], acc[fi][fj], 0, 0, 0);
    }
  }

  // ---- epilogue: repack tile into LDS, then coalesced row writes ----
  __syncthreads();
#pragma unroll
  for (int fj = 0; fj < 4; ++fj) {
    int gcl = wc * 64 + fj * 16 + (lane & 15);
    int gc = colbase + gcl;
    float sc, sh;
    if (OUT_MODE == 0) {
      float s = gamma[gc] * rsqrtf(bvar[gc] + BN_EPS);
      sc = s; sh = bias[gc] * s + beta[gc] - bmean[gc] * s;
    } else {
      sc = 1.f; sh = bias[gc];
    }
#pragma unroll
    for (int fi = 0; fi < 4; ++fi)
#pragma unroll
      for (int r = 0; r < 4; ++r) {
        int rt = wr * 64 + fi * 16 + ((lane >> 4) << 2) + r;
        float v = acc[fi][fj][r] * sc + sh;
        v = (v >= 0.f) ? v : SLOPE * v;
        lds[rt * 128 + gcl] = f2bf(v);
      }
  }
  __syncthreads();
#pragma unroll
  for (int i0 = 0; i0 < 8; ++i0) {
    int i = tid + i0 * 256;
    int row = i >> 4, u4 = i & 15;
    ((uint4*)(outp + (size_t)(rowbase + row) * OUTLD + colbase))[u4] =
        ((const uint4*)lds)[i];
  }
}

// ---------------------------------------------------------------------------
// Fused fc2+fc3+fc4 (plain bf16): per 128-row block, h1 tile staged once;
// h2, h3 live only in LDS (XOR-swizzled); weights staged per phase.
// ---------------------------------------------------------------------------
__global__ __launch_bounds__(256) void fc234_kernel(
    const unsigned short* __restrict__ h1p,
    const unsigned short* __restrict__ W2_, const unsigned short* __restrict__ W3_,
    const unsigned short* __restrict__ W4_,
    const float* __restrict__ b2, const float* __restrict__ b3,
    const float* __restrict__ b4, float* __restrict__ outp) {
  __shared__ unsigned short lds[32768];
  unsigned short* SA  = lds;
  unsigned short* SB  = lds + 16384;
  unsigned short* SH2 = lds + 24576;

  const int tid = threadIdx.x;
  const int wid = tid >> 6;
  const int lane = tid & 63;
  const int rowbase = blockIdx.x * 128;
  const int wr = wid >> 1, wc = wid & 1;

  // ---- stage h1 tile [128][128] (rows 256B = 16 slots) ----
#pragma unroll
  for (int j = 0; j < 8; ++j) {
    int o = j * 4 + wid;
    int rloc = o * 4 + (lane >> 4);
    int slog = (lane & 15) ^ ((rloc & 7) << 1);
    const char* src = (const char*)h1p +
        ((size_t)(rowbase + rloc) * 128) * 2 + (size_t)slog * 16;
    gload16(src, SA + o * 512);
  }
  // ---- stage W2' [64][128] ----
#pragma unroll
  for (int j = 0; j < 4; ++j) {
    int o = j * 4 + wid;
    int rloc = o * 4 + (lane >> 4);
    int slog = (lane & 15) ^ ((rloc & 7) << 1);
    const char* src = (const char*)W2_ +
        ((size_t)rloc * 128) * 2 + (size_t)slog * 16;
    gload16(src, SB + o * 512);
  }
  __syncthreads();

  // ---- fc2: -> 64 cols ----
  f32x4 acc2[4][2];
#pragma unroll
  for (int i = 0; i < 4; ++i) { acc2[i][0] = (f32x4)0.f; acc2[i][1] = (f32x4)0.f; }
#pragma unroll
  for (int kk = 0; kk < 4; ++kk) {
    short8v a[4], b[2];
#pragma unroll
    for (int fi = 0; fi < 4; ++fi) {
      int rt = wr * 64 + fi * 16 + (lane & 15);
      int ph = (kk * 4 + (lane >> 4)) ^ ((rt & 7) << 1);
      a[fi] = *(const short8v*)&SA[rt * 128 + ph * 8];
    }
#pragma unroll
    for (int fj = 0; fj < 2; ++fj) {
      int ct = wc * 32 + fj * 16 + (lane & 15);
      int ph = (kk * 4 + (lane >> 4)) ^ ((ct & 7) << 1);
      b[fj] = *(const short8v*)&SB[ct * 128 + ph * 8];
    }
#pragma unroll
    for (int fi = 0; fi < 4; ++fi)
#pragma unroll
      for (int fj = 0; fj < 2; ++fj)
        acc2[fi][fj] = __builtin_amdgcn_mfma_f32_16x16x32_bf16(
            a[fi], b[fj], acc2[fi][fj], 0, 0, 0);
  }
  __syncthreads();

  // ---- fc2 epilogue -> SH2 [128][64]; stage W3' [64][64] ----
#pragma unroll
  for (int fj = 0; fj < 2; ++fj) {
    int gc = wc * 32 + fj * 16 + (lane & 15);
    float bb = b2[gc];
#pragma unroll
    for (int fi = 0; fi < 4; ++fi)
#pragma unroll
      for (int r = 0; r < 4; ++r) {
        int rt = wr * 64 + fi * 16 + ((lane >> 4) << 2) + r;
        float v = acc2[fi][fj][r] + bb;
        v = (v >= 0.f) ? v : SLOPE * v;
        SH2[rt * 64 + ((gc >> 3) ^ (rt & 7)) * 8 + (gc & 7)] = f2bf(v);
      }
  }
#pragma unroll
  for (int j = 0; j < 2; ++j) {
    int o = j * 4 + wid;
    int rloc = o * 8 + (lane >> 3);
    int slog = (lane & 7) ^ (lane >> 3);
    const char* src = (const char*)W3_ +
        ((size_t)rloc * 64) * 2 + (size_t)slog * 16;
    gload16(src, SB + o * 512);
  }
  __syncthreads();

  // ---- fc3: -> 64 cols ----
  f32x4 acc3[4][2];
#pragma unroll
  for (int i = 0; i < 4; ++i) { acc3[i][0] = (f32x4)0.f; acc3[i][1] = (f32x4)0.f; }
#pragma unroll
  for (int kk = 0; kk < 2; ++kk) {
    short8v a[4], b[2];
#pragma unroll
    for (int fi = 0; fi < 4; ++fi) {
      int rt = wr * 64 + fi * 16 + (lane & 15);
      int ph = (kk * 4 + (lane >> 4)) ^ (rt & 7);
      a[fi] = *(const short8v*)&SH2[rt * 64 + ph * 8];
    }
#pragma unroll
    for (int fj = 0; fj < 2; ++fj) {
      int ct = wc * 32 + fj * 16 + (lane & 15);
      int ph = (kk * 4 + (lane >> 4)) ^ (ct & 7);
      b[fj] = *(const short8v*)&SB[ct * 64 + ph * 8];
    }
#pragma unroll
    for (int fi = 0; fi < 4; ++fi)
#pragma unroll
      for (int fj = 0; fj < 2; ++fj)
        acc3[fi][fj] = __builtin_amdgcn_mfma_f32_16x16x32_bf16(
            a[fi], b[fj], acc3[fi][fj], 0, 0, 0);
  }
  __syncthreads();

  // ---- fc3 epilogue -> SH3 (over SA region); stage W4' [128][64] ----
  unsigned short* SH3 = SA;
#pragma unroll
  for (int fj = 0; fj < 2; ++fj) {
    int gc = wc * 32 + fj * 16 + (lane & 15);
    float bb = b3[gc];
#pragma unroll
    for (int fi = 0; fi < 4; ++fi)
#pragma unroll
      for (int r = 0; r < 4; ++r) {
        int rt = wr * 64 + fi * 16 + ((lane >> 4) << 2) + r;
        float v = acc3[fi][fj][r] + bb;
        v = (v >= 0.f) ? v : SLOPE * v;
        SH3[rt * 64 + ((gc >> 3) ^ (rt & 7)) * 8 + (gc & 7)] = f2bf(v);
      }
  }
#pragma unroll
  for (int j = 0; j < 4; ++j) {
    int o = j * 4 + wid;
    int rloc = o * 8 + (lane >> 3);
    int slog = (lane & 7) ^ (lane >> 3);
    const char* src = (const char*)W4_ +
        ((size_t)rloc * 64) * 2 + (size_t)slog * 16;
    gload16(src, SB + o * 512);
  }
  __syncthreads();

  // ---- fc4: -> 128 cols, f32 out ----
  f32x4 acc4[4][4];
#pragma unroll
  for (int i = 0; i < 4; ++i)
#pragma unroll
    for (int j = 0; j < 4; ++j) acc4[i][j] = (f32x4)0.f;
#pragma unroll
  for (int kk = 0; kk < 2; ++kk) {
    short8v a[4], b[4];
#pragma unroll
    for (int fi = 0; fi < 4; ++fi) {
      int rt = wr * 64 + fi * 16 + (lane & 15);
      int ph = (kk * 4 + (lane >> 4)) ^ (rt & 7);
      a[fi] = *(const short8v*)&SH3[rt * 64 + ph * 8];
    }
#pragma unroll
    for (int fj = 0; fj < 4; ++fj) {
      int ct = wc * 64 + fj * 16 + (lane & 15);
      int ph = (kk * 4 + (lane >> 4)) ^ (ct & 7);
      b[fj] = *(const short8v*)&SB[ct * 64 + ph * 8];
    }
#pragma unroll
    for (int fi = 0; fi < 4; ++fi)
#pragma unroll
      for (int fj = 0; fj < 4; ++fj)
        acc4[fi][fj] = __builtin_amdgcn_mfma_f32_16x16x32_bf16(
            a[fi], b[fj], acc4[fi][fj], 0, 0, 0);
  }

  const int crow0 = rowbase + wr * 64;
#pragma unroll
  for (int fj = 0; fj < 4; ++fj) {
    int gc = wc * 64 + fj * 16 + (lane & 15);
    float bb = b4[gc];
#pragma unroll
    for (int fi = 0; fi < 4; ++fi)
#pragma unroll
      for (int r = 0; r < 4; ++r) {
        int gr = crow0 + fi * 16 + ((lane >> 4) << 2) + r;
        if (gr < N_NODES) {
          float v = acc4[fi][fj][r] + bb;
          v = (v >= 0.f) ? v : SLOPE * v;
          outp[(size_t)gr * FEAT + gc] = v;
        }
      }
  }
}

extern "C" void kernel_launch(void* const* d_in, const int* in_sizes, int n_in,
                              void* d_out, int out_size, void* d_ws, size_t ws_size,
                              hipStream_t stream) {
  const float* nf    = (const float*)d_in[0];
  const float* noise = (const float*)d_in[1];
  const int*   ei    = (const int*)d_in[2];
  const float* Wl    = (const float*)d_in[4];
  const float* bl    = (const float*)d_in[5];
  const float* Wr    = (const float*)d_in[6];
  const float* gam   = (const float*)d_in[7];
  const float* bet   = (const float*)d_in[8];
  const float* bmean = (const float*)d_in[9];
  const float* bvar  = (const float*)d_in[10];
  const float* fc1w  = (const float*)d_in[11];
  const float* fc1b  = (const float*)d_in[12];
  const float* fc2w  = (const float*)d_in[13];
  const float* fc2b  = (const float*)d_in[14];
  const float* fc3w  = (const float*)d_in[15];
  const float* fc3b  = (const float*)d_in[16];
  const float* fc4w  = (const float*)d_in[17];
  const float* fc4b  = (const float*)d_in[18];
  float* outp = (float*)d_out;

  // ---- workspace (ushort units unless noted); total ~65 MB ----
  unsigned short* xa  = (unsigned short*)d_ws;             // [NPAD][384]: [agg|x]
  unsigned short* hp  = xa + (size_t)NPAD * 384;           // [NPAD][256]
  unsigned short* Wc_ = hp + (size_t)NPAD * 256;           // 256*384
  unsigned short* W1_ = Wc_ + 256 * 384;                   // 128*256
  unsigned short* W2_ = W1_ + 128 * 256;                   // 64*128
  unsigned short* W3_ = W2_ + 64 * 128;                    // 64*64
  unsigned short* W4_ = W3_ + 64 * 64;                     // 128*64
  int* deg    = (int*)(W4_ + 128 * 64);                    // N
  int* cursor = deg + N_NODES;                             // N
  int* bsum   = cursor + N_NODES;                          // 256
  unsigned short* h1p = xa;                                // [NPAD][128] (xa dead after combine)
  int* csr = (int*)d_out;                                  // E ints (dead before fc234 writes)

  hipMemsetAsync(deg, 0, (size_t)N_NODES * sizeof(int), stream);

  wconv_kernel<<<592, 256, 0, stream>>>(Wl, Wr, fc1w, fc2w, fc3w, fc4w,
                                        Wc_, W1_, W2_, W3_, W4_);
  xconv_kernel<<<(N_NODES * 24 + 255) / 256, 256, 0, stream>>>(nf, noise, xa);

  // --- CSR build ---
  deg_count_kernel<<<(E_EDGES + 255) / 256, 256, 0, stream>>>(ei, deg);
  block_sum_kernel<<<NB, 256, 0, stream>>>(deg, bsum);
  scan_bsum_kernel<<<1, 256, 0, stream>>>(bsum);
  scan_chunk_kernel<<<NB, 256, 0, stream>>>(deg, bsum, cursor);
  fill_kernel<<<(E_EDGES + 255) / 256, 256, 0, stream>>>(ei, cursor, csr);

  // --- Aggregate (bf16 source) ---
  gather_kernel<<<(N_NODES + 3) / 4, 256, 0, stream>>>(csr, cursor, deg, xa);

  const int RB = NPAD / 128;  // 391

  // --- combine: K=384 (rows [agg 192 | x 192]), out 256 cols + BN+lrelu ---
  gemm_plain<384, 384, 256, 0><<<dim3(RB, 2), 256, 0, stream>>>(
      xa, Wc_, bl, gam, bet, bmean, bvar, hp);
  // --- fc1: K=256, out 128 cols + bias+lrelu ---
  gemm_plain<256, 256, 128, 1><<<dim3(RB, 1), 256, 0, stream>>>(
      hp, W1_, fc1b, nullptr, nullptr, nullptr, nullptr, h1p);
  // --- fused fc2+fc3+fc4 -> f32 out ---
  fc234_kernel<<<RB, 256, 0, stream>>>(h1p, W2_, W3_, W4_,
                                       fc2b, fc3b, fc4b, outp);
}

// Round 7
// 153.037 us; speedup vs baseline: 6.4235x; 1.3662x over previous
//
#include <hip/hip_runtime.h>

#define N_NODES 50000
#define NPAD    50048   // 391 * 128
#define FEAT    128
#define NZ      64
#define E_EDGES 800000
#define BN_EPS  1e-5f
#define SLOPE   0.2f
#define NB      196     // ceil(50048 / 256) == ceil(50000/256)
#define NBUK    391     // buckets of 128 dst nodes (NPAD/128)
#define NCHK    128     // edge chunks
#define CE      6250    // edges per chunk (E/NCHK exactly)

typedef __attribute__((ext_vector_type(8))) short short8v;
typedef __attribute__((ext_vector_type(4))) float f32x4;

// ---------------- bf16 helpers ----------------
__device__ __forceinline__ unsigned short f2bf(float v) {
  union { float f; unsigned u; } c; c.f = v;
  unsigned r = c.u + 0x7FFFu + ((c.u >> 16) & 1u);
  return (unsigned short)(r >> 16);
}
__device__ __forceinline__ float bflo32(unsigned u) {
  union { unsigned x; float f; } c; c.x = u << 16; return c.f;
}
__device__ __forceinline__ float bfhi32(unsigned u) {
  union { unsigned x; float f; } c; c.x = u & 0xFFFF0000u; return c.f;
}

__device__ __forceinline__ void gload16(const void* src, const void* lds) {
  __builtin_amdgcn_global_load_lds(
      (const __attribute__((address_space(1))) unsigned int*)src,
      (__attribute__((address_space(3))) unsigned int*)lds, 16, 0, 0);
}

// ---------------------------------------------------------------------------
// x-table conversion: nf/noise f32 -> xa[n][192..384) bf16.
// ---------------------------------------------------------------------------
__global__ __launch_bounds__(256) void xconv_kernel(
    const float* __restrict__ nf, const float* __restrict__ noise,
    unsigned short* __restrict__ xa) {
  int i = blockIdx.x * 256 + threadIdx.x;
  if (i >= N_NODES * 24) return;
  int n = i / 24, s = i % 24;
  float4 va, vb;
  if (s < 16) {
    va = ((const float4*)nf)[(size_t)n * 32 + s * 2];
    vb = ((const float4*)nf)[(size_t)n * 32 + s * 2 + 1];
  } else {
    int t = s - 16;
    va = ((const float4*)noise)[(size_t)n * 16 + t * 2];
    vb = ((const float4*)noise)[(size_t)n * 16 + t * 2 + 1];
  }
  unsigned p0 = (unsigned)f2bf(va.x) | ((unsigned)f2bf(va.y) << 16);
  unsigned p1 = (unsigned)f2bf(va.z) | ((unsigned)f2bf(va.w) << 16);
  unsigned p2 = (unsigned)f2bf(vb.x) | ((unsigned)f2bf(vb.y) << 16);
  unsigned p3 = (unsigned)f2bf(vb.z) | ((unsigned)f2bf(vb.w) << 16);
  *(uint4*)&xa[(size_t)n * 384 + 192 + s * 8] = make_uint4(p0, p1, p2, p3);
}

// ---------------------------------------------------------------------------
// CSR build via two-level LDS counting sort (no global atomics).
// ---------------------------------------------------------------------------
// Pass 1: per-chunk bucket histogram (bucket = dst>>7). cnt[b*NCHK + c].
__global__ __launch_bounds__(256) void hist_kernel(
    const int* __restrict__ ei, int* __restrict__ cnt) {
  __shared__ int h[NBUK];
  int c = blockIdx.x, t = threadIdx.x;
  for (int i = t; i < NBUK; i += 256) h[i] = 0;
  __syncthreads();
  int e0 = c * CE;
  for (int e = e0 + t; e < e0 + CE; e += 256)
    atomicAdd(&h[ei[E_EDGES + e] >> 7], 1);
  __syncthreads();
  for (int i = t; i < NBUK; i += 256) cnt[i * NCHK + c] = h[i];
}

// Generic 3-kernel exclusive scan (length LEN <= NB*256).
template <int LEN>
__global__ __launch_bounds__(256) void block_sum_kernel(
    const int* __restrict__ in, int* __restrict__ bsum) {
  __shared__ int sh[256];
  int i = blockIdx.x * 256 + threadIdx.x;
  sh[threadIdx.x] = (i < LEN) ? in[i] : 0;
  __syncthreads();
  for (int s = 128; s > 0; s >>= 1) {
    if (threadIdx.x < s) sh[threadIdx.x] += sh[threadIdx.x + s];
    __syncthreads();
  }
  if (threadIdx.x == 0) bsum[blockIdx.x] = sh[0];
}

__global__ __launch_bounds__(256) void scan_bsum_kernel(int* __restrict__ bsum) {
  __shared__ int sh[256];
  int t = threadIdx.x;
  sh[t] = (t < NB) ? bsum[t] : 0;
  __syncthreads();
  for (int off = 1; off < 256; off <<= 1) {
    int v = (t >= off) ? sh[t - off] : 0;
    __syncthreads();
    sh[t] += v;
    __syncthreads();
  }
  if (t < NB) bsum[t] = (t == 0) ? 0 : sh[t - 1];
}

template <int LEN>
__global__ __launch_bounds__(256) void scan_chunk_kernel(
    const int* __restrict__ in, const int* __restrict__ bsum,
    int* __restrict__ out) {
  __shared__ int sh[256];
  int t = threadIdx.x;
  int i = blockIdx.x * 256 + t;
  int v = (i < LEN) ? in[i] : 0;
  sh[t] = v;
  __syncthreads();
  for (int off = 1; off < 256; off <<= 1) {
    int u = (t >= off) ? sh[t - off] : 0;
    __syncthreads();
    sh[t] += u;
    __syncthreads();
  }
  if (i < LEN) out[i] = bsum[blockIdx.x] + sh[t] - v;  // exclusive
}

// Pass 2: scatter edges into bucket-sorted ebuf via LDS cursors.
// Packed entry: (dst&127)<<16 | src  (src < 50000 < 2^16).
__global__ __launch_bounds__(256) void scatter_kernel(
    const int* __restrict__ ei, const int* __restrict__ ebase,
    unsigned* __restrict__ ebuf) {
  __shared__ int cur[NBUK];
  int c = blockIdx.x, t = threadIdx.x;
  for (int i = t; i < NBUK; i += 256) cur[i] = ebase[i * NCHK + c];
  __syncthreads();
  int e0 = c * CE;
  for (int e = e0 + t; e < e0 + CE; e += 256) {
    int s = ei[e], d = ei[E_EDGES + e];
    int p = atomicAdd(&cur[d >> 7], 1);
    ebuf[p] = ((unsigned)(d & 127) << 16) | (unsigned)s;
  }
}

// Pass 3: per-bucket sort (one block per bucket): 128-bin LDS histogram +
// scan -> writes deg/cursor for the bucket's nodes, places src into csr.
__global__ __launch_bounds__(256) void sortb_kernel(
    const unsigned* __restrict__ ebuf, const int* __restrict__ ebase,
    int* __restrict__ csr, int* __restrict__ deg, int* __restrict__ cursor) {
  __shared__ int h[128], sc[128], curn[128];
  int b = blockIdx.x, t = threadIdx.x;
  int beg = ebase[b * NCHK];
  int endb = (b == NBUK - 1) ? E_EDGES : ebase[(b + 1) * NCHK];
  if (t < 128) h[t] = 0;
  __syncthreads();
  for (int i = beg + t; i < endb; i += 256) atomicAdd(&h[ebuf[i] >> 16], 1);
  __syncthreads();
  if (t < 128) sc[t] = h[t];
  __syncthreads();
  for (int off = 1; off < 128; off <<= 1) {
    int v = (t >= off && t < 128) ? sc[t - off] : 0;
    __syncthreads();
    if (t < 128) sc[t] += v;
    __syncthreads();
  }
  if (t < 128) {
    curn[t] = sc[t] - h[t];  // exclusive
    int n = b * 128 + t;
    if (n < N_NODES) {
      deg[n] = h[t];
      cursor[n] = beg + sc[t];  // row end
    }
  }
  __syncthreads();
  for (int i = beg + t; i < endb; i += 256) {
    unsigned u = ebuf[i];
    int p = atomicAdd(&curn[u >> 16], 1);
    csr[beg + p] = (int)(u & 0xFFFFu);
  }
}

// ---------------------------------------------------------------------------
// Gather-aggregate (bf16 source): one wave per node; lane l<48 owns 4
// channels via one uint2 (8B) load per neighbor row. 4-wide unroll.
// ---------------------------------------------------------------------------
__global__ __launch_bounds__(256) void gather_kernel(
    const int* __restrict__ csr, const int* __restrict__ cursor,
    const int* __restrict__ deg, unsigned short* __restrict__ xa) {
  int wid = (blockIdx.x * blockDim.x + threadIdx.x) >> 6;
  int lane = threadIdx.x & 63;
  if (wid >= N_NODES) return;
  int d = deg[wid];
  int end = cursor[wid];
  int start = end - d;
  const bool act = lane < 48;
  const size_t lo = (size_t)lane * 4 + 192;  // ushort offset within row

  float a0 = 0.f, a1 = 0.f, a2 = 0.f, a3 = 0.f;
  float b0 = 0.f, b1 = 0.f, b2 = 0.f, b3 = 0.f;
  float c0 = 0.f, c1 = 0.f, c2 = 0.f, c3 = 0.f;
  float e0 = 0.f, e1 = 0.f, e2 = 0.f, e3 = 0.f;
  int j = start;
  for (; j + 3 < end; j += 4) {
    int sa = csr[j], sb = csr[j + 1], sc = csr[j + 2], sd = csr[j + 3];
    if (act) {
      uint2 va = *(const uint2*)&xa[(size_t)sa * 384 + lo];
      uint2 vb = *(const uint2*)&xa[(size_t)sb * 384 + lo];
      uint2 vc = *(const uint2*)&xa[(size_t)sc * 384 + lo];
      uint2 ve = *(const uint2*)&xa[(size_t)sd * 384 + lo];
      a0 += bflo32(va.x); a1 += bfhi32(va.x); a2 += bflo32(va.y); a3 += bfhi32(va.y);
      b0 += bflo32(vb.x); b1 += bfhi32(vb.x); b2 += bflo32(vb.y); b3 += bfhi32(vb.y);
      c0 += bflo32(vc.x); c1 += bfhi32(vc.x); c2 += bflo32(vc.y); c3 += bfhi32(vc.y);
      e0 += bflo32(ve.x); e1 += bfhi32(ve.x); e2 += bflo32(ve.y); e3 += bfhi32(ve.y);
    }
  }
  for (; j < end; ++j) {
    int sa = csr[j];
    if (act) {
      uint2 va = *(const uint2*)&xa[(size_t)sa * 384 + lo];
      a0 += bflo32(va.x); a1 += bfhi32(va.x); a2 += bflo32(va.y); a3 += bfhi32(va.y);
    }
  }
  if (act) {
    float inv = 1.0f / fmaxf((float)d, 1.0f);
    float m0 = ((a0 + b0) + (c0 + e0)) * inv;
    float m1 = ((a1 + b1) + (c1 + e1)) * inv;
    float m2 = ((a2 + b2) + (c2 + e2)) * inv;
    float m3 = ((a3 + b3) + (c3 + e3)) * inv;
    unsigned r0 = (unsigned)f2bf(m0) | ((unsigned)f2bf(m1) << 16);
    unsigned r1 = (unsigned)f2bf(m2) | ((unsigned)f2bf(m3) << 16);
    *(uint2*)&xa[(size_t)wid * 384 + (size_t)lane * 4] = make_uint2(r0, r1);
  }
}

// ---------------------------------------------------------------------------
// Weight conversion (plain bf16, k-major per output column).
// ---------------------------------------------------------------------------
__global__ __launch_bounds__(256) void wconv_kernel(
    const float* __restrict__ Wl, const float* __restrict__ Wr,
    const float* __restrict__ W1, const float* __restrict__ W2,
    const float* __restrict__ W3, const float* __restrict__ W4,
    unsigned short* __restrict__ Wc_, unsigned short* __restrict__ W1_,
    unsigned short* __restrict__ W2_, unsigned short* __restrict__ W3_,
    unsigned short* __restrict__ W4_) {
  int idx = blockIdx.x * 256 + threadIdx.x;
  if (idx < 49152) {                       // Wl: K=192, M=256
    int k = idx % 192, m = idx / 192;
    Wc_[(size_t)m * 384 + k] = f2bf(Wl[(size_t)k * 256 + m]);
  } else if (idx < 98304) {                // Wr
    int local = idx - 49152;
    int k = local % 192, m = local / 192;
    Wc_[(size_t)m * 384 + 192 + k] = f2bf(Wr[(size_t)k * 256 + m]);
  } else if (idx < 131072) {               // W1: K=256, M=128
    int local = idx - 98304;
    int k = local % 256, m = local / 256;
    W1_[(size_t)m * 256 + k] = f2bf(W1[(size_t)k * 128 + m]);
  } else if (idx < 139264) {               // W2: K=128, M=64
    int local = idx - 131072;
    int k = local % 128, m = local / 128;
    W2_[(size_t)m * 128 + k] = f2bf(W2[(size_t)k * 64 + m]);
  } else if (idx < 143360) {               // W3: K=64, M=64
    int local = idx - 139264;
    int k = local % 64, m = local / 64;
    W3_[(size_t)m * 64 + k] = f2bf(W3[(size_t)k * 64 + m]);
  } else if (idx < 151552) {               // W4: K=64, M=128
    int local = idx - 143360;
    int k = local % 64, m = local / 64;
    W4_[(size_t)m * 64 + k] = f2bf(W4[(size_t)k * 128 + m]);
  }
}

// ---------------------------------------------------------------------------
// Plain bf16 MFMA GEMM (unchanged from round 6).
// ---------------------------------------------------------------------------
template <int KBASE, int ALD, int OUTLD, int OUT_MODE>
__global__ __launch_bounds__(256) void gemm_plain(
    const unsigned short* __restrict__ Ab, const unsigned short* __restrict__ Bb,
    const float* __restrict__ bias, const float* __restrict__ gamma,
    const float* __restrict__ beta, const float* __restrict__ bmean,
    const float* __restrict__ bvar, unsigned short* __restrict__ outp) {
  constexpr int BM = 128, MTILE = 128, BK = 64;
  constexpr int NITER = KBASE / BK;

  __shared__ unsigned short lds[16384];  // 32 KB
  unsigned short* sA = lds;
  unsigned short* sB = lds + 8192;

  const int tid = threadIdx.x;
  const int wid = tid >> 6;
  const int lane = tid & 63;
  const int rowbase = blockIdx.x * BM;
  const int colbase = blockIdx.y * MTILE;
  const int wr = wid >> 1, wc = wid & 1;

  f32x4 acc[4][4];
#pragma unroll
  for (int i = 0; i < 4; ++i)
#pragma unroll
    for (int j = 0; j < 4; ++j) acc[i][j] = (f32x4)0.f;

  for (int kt = 0; kt < NITER; ++kt) {
    const int kb = kt * BK;
    __syncthreads();
#pragma unroll
    for (int j = 0; j < 4; ++j) {
      int rb = j * 4 + wid;
      int row = rb * 8 + (lane >> 3);
      int slog = (lane & 7) ^ (lane >> 3);
      const char* src = (const char*)Bb +
          ((size_t)(colbase + row) * KBASE + kb) * 2 + (size_t)slog * 16;
      gload16(src, sB + rb * 512);
    }
#pragma unroll
    for (int j = 0; j < 4; ++j) {
      int rb = j * 4 + wid;
      int row = rb * 8 + (lane >> 3);
      int slog = (lane & 7) ^ (lane >> 3);
      const char* src = (const char*)Ab +
          ((size_t)(rowbase + row) * ALD + kb) * 2 + (size_t)slog * 16;
      gload16(src, sA + rb * 512);
    }
    __syncthreads();

#pragma unroll
    for (int kk = 0; kk < 2; ++kk) {
      short8v a[4], b[4];
#pragma unroll
      for (int fi = 0; fi < 4; ++fi) {
        int rt = wr * 64 + fi * 16 + (lane & 15);
        int sl = (kk * 4 + (lane >> 4)) ^ (rt & 7);
        a[fi] = *(const short8v*)&sA[rt * 64 + sl * 8];
      }
#pragma unroll
      for (int fj = 0; fj < 4; ++fj) {
        int ct = wc * 64 + fj * 16 + (lane & 15);
        int sl = (kk * 4 + (lane >> 4)) ^ (ct & 7);
        b[fj] = *(const short8v*)&sB[ct * 64 + sl * 8];
      }
#pragma unroll
      for (int fi = 0; fi < 4; ++fi)
#pragma unroll
        for (int fj = 0; fj < 4; ++fj)
          acc[fi][fj] = __builtin_amdgcn_mfma_f32_16x16x32_bf16(
              a[fi], b[fj], acc[fi][fj], 0, 0, 0);
    }
  }

  __syncthreads();
#pragma unroll
  for (int fj = 0; fj < 4; ++fj) {
    int gcl = wc * 64 + fj * 16 + (lane & 15);
    int gc = colbase + gcl;
    float sc, sh;
    if (OUT_MODE == 0) {
      float s = gamma[gc] * rsqrtf(bvar[gc] + BN_EPS);
      sc = s; sh = bias[gc] * s + beta[gc] - bmean[gc] * s;
    } else {
      sc = 1.f; sh = bias[gc];
    }
#pragma unroll
    for (int fi = 0; fi < 4; ++fi)
#pragma unroll
      for (int r = 0; r < 4; ++r) {
        int rt = wr * 64 + fi * 16 + ((lane >> 4) << 2) + r;
        float v = acc[fi][fj][r] * sc + sh;
        v = (v >= 0.f) ? v : SLOPE * v;
        lds[rt * 128 + gcl] = f2bf(v);
      }
  }
  __syncthreads();
#pragma unroll
  for (int i0 = 0; i0 < 8; ++i0) {
    int i = tid + i0 * 256;
    int row = i >> 4, u4 = i & 15;
    ((uint4*)(outp + (size_t)(rowbase + row) * OUTLD + colbase))[u4] =
        ((const uint4*)lds)[i];
  }
}

// ---------------------------------------------------------------------------
// Fused fc2+fc3+fc4 (unchanged from round 6).
// ---------------------------------------------------------------------------
__global__ __launch_bounds__(256) void fc234_kernel(
    const unsigned short* __restrict__ h1p,
    const unsigned short* __restrict__ W2_, const unsigned short* __restrict__ W3_,
    const unsigned short* __restrict__ W4_,
    const float* __restrict__ b2, const float* __restrict__ b3,
    const float* __restrict__ b4, float* __restrict__ outp) {
  __shared__ unsigned short lds[32768];
  unsigned short* SA  = lds;
  unsigned short* SB  = lds + 16384;
  unsigned short* SH2 = lds + 24576;

  const int tid = threadIdx.x;
  const int wid = tid >> 6;
  const int lane = tid & 63;
  const int rowbase = blockIdx.x * 128;
  const int wr = wid >> 1, wc = wid & 1;

#pragma unroll
  for (int j = 0; j < 8; ++j) {
    int o = j * 4 + wid;
    int rloc = o * 4 + (lane >> 4);
    int slog = (lane & 15) ^ ((rloc & 7) << 1);
    const char* src = (const char*)h1p +
        ((size_t)(rowbase + rloc) * 128) * 2 + (size_t)slog * 16;
    gload16(src, SA + o * 512);
  }
#pragma unroll
  for (int j = 0; j < 4; ++j) {
    int o = j * 4 + wid;
    int rloc = o * 4 + (lane >> 4);
    int slog = (lane & 15) ^ ((rloc & 7) << 1);
    const char* src = (const char*)W2_ +
        ((size_t)rloc * 128) * 2 + (size_t)slog * 16;
    gload16(src, SB + o * 512);
  }
  __syncthreads();

  f32x4 acc2[4][2];
#pragma unroll
  for (int i = 0; i < 4; ++i) { acc2[i][0] = (f32x4)0.f; acc2[i][1] = (f32x4)0.f; }
#pragma unroll
  for (int kk = 0; kk < 4; ++kk) {
    short8v a[4], b[2];
#pragma unroll
    for (int fi = 0; fi < 4; ++fi) {
      int rt = wr * 64 + fi * 16 + (lane & 15);
      int ph = (kk * 4 + (lane >> 4)) ^ ((rt & 7) << 1);
      a[fi] = *(const short8v*)&SA[rt * 128 + ph * 8];
    }
#pragma unroll
    for (int fj = 0; fj < 2; ++fj) {
      int ct = wc * 32 + fj * 16 + (lane & 15);
      int ph = (kk * 4 + (lane >> 4)) ^ ((ct & 7) << 1);
      b[fj] = *(const short8v*)&SB[ct * 128 + ph * 8];
    }
#pragma unroll
    for (int fi = 0; fi < 4; ++fi)
#pragma unroll
      for (int fj = 0; fj < 2; ++fj)
        acc2[fi][fj] = __builtin_amdgcn_mfma_f32_16x16x32_bf16(
            a[fi], b[fj], acc2[fi][fj], 0, 0, 0);
  }
  __syncthreads();

#pragma unroll
  for (int fj = 0; fj < 2; ++fj) {
    int gc = wc * 32 + fj * 16 + (lane & 15);
    float bb = b2[gc];
#pragma unroll
    for (int fi = 0; fi < 4; ++fi)
#pragma unroll
      for (int r = 0; r < 4; ++r) {
        int rt = wr * 64 + fi * 16 + ((lane >> 4) << 2) + r;
        float v = acc2[fi][fj][r] + bb;
        v = (v >= 0.f) ? v : SLOPE * v;
        SH2[rt * 64 + ((gc >> 3) ^ (rt & 7)) * 8 + (gc & 7)] = f2bf(v);
      }
  }
#pragma unroll
  for (int j = 0; j < 2; ++j) {
    int o = j * 4 + wid;
    int rloc = o * 8 + (lane >> 3);
    int slog = (lane & 7) ^ (lane >> 3);
    const char* src = (const char*)W3_ +
        ((size_t)rloc * 64) * 2 + (size_t)slog * 16;
    gload16(src, SB + o * 512);
  }
  __syncthreads();

  f32x4 acc3[4][2];
#pragma unroll
  for (int i = 0; i < 4; ++i) { acc3[i][0] = (f32x4)0.f; acc3[i][1] = (f32x4)0.f; }
#pragma unroll
  for (int kk = 0; kk < 2; ++kk) {
    short8v a[4], b[2];
#pragma unroll
    for (int fi = 0; fi < 4; ++fi) {
      int rt = wr * 64 + fi * 16 + (lane & 15);
      int ph = (kk * 4 + (lane >> 4)) ^ (rt & 7);
      a[fi] = *(const short8v*)&SH2[rt * 64 + ph * 8];
    }
#pragma unroll
    for (int fj = 0; fj < 2; ++fj) {
      int ct = wc * 32 + fj * 16 + (lane & 15);
      int ph = (kk * 4 + (lane >> 4)) ^ (ct & 7);
      b[fj] = *(const short8v*)&SB[ct * 64 + ph * 8];
    }
#pragma unroll
    for (int fi = 0; fi < 4; ++fi)
#pragma unroll
      for (int fj = 0; fj < 2; ++fj)
        acc3[fi][fj] = __builtin_amdgcn_mfma_f32_16x16x32_bf16(
            a[fi], b[fj], acc3[fi][fj], 0, 0, 0);
  }
  __syncthreads();

  unsigned short* SH3 = SA;
#pragma unroll
  for (int fj = 0; fj < 2; ++fj) {
    int gc = wc * 32 + fj * 16 + (lane & 15);
    float bb = b3[gc];
#pragma unroll
    for (int fi = 0; fi < 4; ++fi)
#pragma unroll
      for (int r = 0; r < 4; ++r) {
        int rt = wr * 64 + fi * 16 + ((lane >> 4) << 2) + r;
        float v = acc3[fi][fj][r] + bb;
        v = (v >= 0.f) ? v : SLOPE * v;
        SH3[rt * 64 + ((gc >> 3) ^ (rt & 7)) * 8 + (gc & 7)] = f2bf(v);
      }
  }
#pragma unroll
  for (int j = 0; j < 4; ++j) {
    int o = j * 4 + wid;
    int rloc = o * 8 + (lane >> 3);
    int slog = (lane & 7) ^ (lane >> 3);
    const char* src = (const char*)W4_ +
        ((size_t)rloc * 64) * 2 + (size_t)slog * 16;
    gload16(src, SB + o * 512);
  }
  __syncthreads();

  f32x4 acc4[4][4];
#pragma unroll
  for (int i = 0; i < 4; ++i)
#pragma unroll
    for (int j = 0; j < 4; ++j) acc4[i][j] = (f32x4)0.f;
#pragma unroll
  for (int kk = 0; kk < 2; ++kk) {
    short8v a[4], b[4];
#pragma unroll
    for (int fi = 0; fi < 4; ++fi) {
      int rt = wr * 64 + fi * 16 + (lane & 15);
      int ph = (kk * 4 + (lane >> 4)) ^ (rt & 7);
      a[fi] = *(const short8v*)&SH3[rt * 64 + ph * 8];
    }
#pragma unroll
    for (int fj = 0; fj < 4; ++fj) {
      int ct = wc * 64 + fj * 16 + (lane & 15);
      int ph = (kk * 4 + (lane >> 4)) ^ (ct & 7);
      b[fj] = *(const short8v*)&SB[ct * 64 + ph * 8];
    }
#pragma unroll
    for (int fi = 0; fi < 4; ++fi)
#pragma unroll
      for (int fj = 0; fj < 4; ++fj)
        acc4[fi][fj] = __builtin_amdgcn_mfma_f32_16x16x32_bf16(
            a[fi], b[fj], acc4[fi][fj], 0, 0, 0);
  }

  const int crow0 = rowbase + wr * 64;
#pragma unroll
  for (int fj = 0; fj < 4; ++fj) {
    int gc = wc * 64 + fj * 16 + (lane & 15);
    float bb = b4[gc];
#pragma unroll
    for (int fi = 0; fi < 4; ++fi)
#pragma unroll
      for (int r = 0; r < 4; ++r) {
        int gr = crow0 + fi * 16 + ((lane >> 4) << 2) + r;
        if (gr < N_NODES) {
          float v = acc4[fi][fj][r] + bb;
          v = (v >= 0.f) ? v : SLOPE * v;
          outp[(size_t)gr * FEAT + gc] = v;
        }
      }
  }
}

extern "C" void kernel_launch(void* const* d_in, const int* in_sizes, int n_in,
                              void* d_out, int out_size, void* d_ws, size_t ws_size,
                              hipStream_t stream) {
  const float* nf    = (const float*)d_in[0];
  const float* noise = (const float*)d_in[1];
  const int*   ei    = (const int*)d_in[2];
  const float* Wl    = (const float*)d_in[4];
  const float* bl    = (const float*)d_in[5];
  const float* Wr    = (const float*)d_in[6];
  const float* gam   = (const float*)d_in[7];
  const float* bet   = (const float*)d_in[8];
  const float* bmean = (const float*)d_in[9];
  const float* bvar  = (const float*)d_in[10];
  const float* fc1w  = (const float*)d_in[11];
  const float* fc1b  = (const float*)d_in[12];
  const float* fc2w  = (const float*)d_in[13];
  const float* fc2b  = (const float*)d_in[14];
  const float* fc3w  = (const float*)d_in[15];
  const float* fc3b  = (const float*)d_in[16];
  const float* fc4w  = (const float*)d_in[17];
  const float* fc4b  = (const float*)d_in[18];
  float* outp = (float*)d_out;

  // ---- workspace (ushort units unless noted) ----
  unsigned short* xa  = (unsigned short*)d_ws;             // [NPAD][384]: [agg|x]
  unsigned short* hp  = xa + (size_t)NPAD * 384;           // [NPAD][256]
  unsigned short* Wc_ = hp + (size_t)NPAD * 256;           // 256*384
  unsigned short* W1_ = Wc_ + 256 * 384;                   // 128*256
  unsigned short* W2_ = W1_ + 128 * 256;                   // 64*128
  unsigned short* W3_ = W2_ + 64 * 128;                    // 64*64
  unsigned short* W4_ = W3_ + 64 * 64;                     // 128*64
  int* deg    = (int*)(W4_ + 128 * 64);                    // N
  int* cursor = deg + N_NODES;                             // N
  int* bsum   = cursor + N_NODES;                          // 256
  int* cnt    = bsum + 256;                                // NBUK*NCHK = 50048
  int* ebase  = cnt + NBUK * NCHK;                         // 50048
  unsigned short* h1p = xa;                                // [NPAD][128] (xa dead after combine)
  // d_out scratch (dead before fc234 writes): csr + ebuf
  int*      csr  = (int*)d_out;                            // E ints
  unsigned* ebuf = (unsigned*)d_out + E_EDGES;             // E uints

  wconv_kernel<<<592, 256, 0, stream>>>(Wl, Wr, fc1w, fc2w, fc3w, fc4w,
                                        Wc_, W1_, W2_, W3_, W4_);
  xconv_kernel<<<(N_NODES * 24 + 255) / 256, 256, 0, stream>>>(nf, noise, xa);

  // --- CSR build: LDS counting sort, no global atomics ---
  hist_kernel<<<NCHK, 256, 0, stream>>>(ei, cnt);
  block_sum_kernel<NBUK * NCHK><<<NB, 256, 0, stream>>>(cnt, bsum);
  scan_bsum_kernel<<<1, 256, 0, stream>>>(bsum);
  scan_chunk_kernel<NBUK * NCHK><<<NB, 256, 0, stream>>>(cnt, bsum, ebase);
  scatter_kernel<<<NCHK, 256, 0, stream>>>(ei, ebase, ebuf);
  sortb_kernel<<<NBUK, 256, 0, stream>>>(ebuf, ebase, csr, deg, cursor);

  // --- Aggregate ---
  gather_kernel<<<(N_NODES + 3) / 4, 256, 0, stream>>>(csr, cursor, deg, xa);

  const int RB = NPAD / 128;  // 391

  // --- combine: K=384 (rows [agg 192 | x 192]), out 256 cols + BN+lrelu ---
  gemm_plain<384, 384, 256, 0><<<dim3(RB, 2), 256, 0, stream>>>(
      xa, Wc_, bl, gam, bet, bmean, bvar, hp);
  // --- fc1: K=256, out 128 cols + bias+lrelu ---
  gemm_plain<256, 256, 128, 1><<<dim3(RB, 1), 256, 0, stream>>>(
      hp, W1_, fc1b, nullptr, nullptr, nullptr, nullptr, h1p);
  // --- fused fc2+fc3+fc4 -> f32 out ---
  fc234_kernel<<<RB, 256, 0, stream>>>(h1p, W2_, W3_, W4_,
                                       fc2b, fc3b, fc4b, outp);
}

// Round 8
// 151.716 us; speedup vs baseline: 6.4795x; 1.0087x over previous
//
#include <hip/hip_runtime.h>

#define N_NODES 50000
#define NPAD    50048   // 391 * 128
#define FEAT    128
#define NZ      64
#define E_EDGES 800000
#define BN_EPS  1e-5f
#define SLOPE   0.2f
#define NB      196     // ceil(50048 / 256)
#define NBUK    391     // buckets of 128 dst nodes (NPAD/128)
#define NCHK    128     // edge chunks
#define CE      6250    // edges per chunk (E/NCHK exactly)

typedef __attribute__((ext_vector_type(8))) short short8v;
typedef __attribute__((ext_vector_type(4))) float f32x4;

// ---------------- bf16 helpers ----------------
__device__ __forceinline__ unsigned short f2bf(float v) {
  union { float f; unsigned u; } c; c.f = v;
  unsigned r = c.u + 0x7FFFu + ((c.u >> 16) & 1u);
  return (unsigned short)(r >> 16);
}
__device__ __forceinline__ float bflo32(unsigned u) {
  union { unsigned x; float f; } c; c.x = u << 16; return c.f;
}
__device__ __forceinline__ float bfhi32(unsigned u) {
  union { unsigned x; float f; } c; c.x = u & 0xFFFF0000u; return c.f;
}

__device__ __forceinline__ void gload16(const void* src, const void* lds) {
  __builtin_amdgcn_global_load_lds(
      (const __attribute__((address_space(1))) unsigned int*)src,
      (__attribute__((address_space(3))) unsigned int*)lds, 16, 0, 0);
}

// ---------------------------------------------------------------------------
// x-table conversion: nf/noise f32 -> xa[n][192..384) bf16.
// ---------------------------------------------------------------------------
__global__ __launch_bounds__(256) void xconv_kernel(
    const float* __restrict__ nf, const float* __restrict__ noise,
    unsigned short* __restrict__ xa) {
  int i = blockIdx.x * 256 + threadIdx.x;
  if (i >= N_NODES * 24) return;
  int n = i / 24, s = i % 24;
  float4 va, vb;
  if (s < 16) {
    va = ((const float4*)nf)[(size_t)n * 32 + s * 2];
    vb = ((const float4*)nf)[(size_t)n * 32 + s * 2 + 1];
  } else {
    int t = s - 16;
    va = ((const float4*)noise)[(size_t)n * 16 + t * 2];
    vb = ((const float4*)noise)[(size_t)n * 16 + t * 2 + 1];
  }
  unsigned p0 = (unsigned)f2bf(va.x) | ((unsigned)f2bf(va.y) << 16);
  unsigned p1 = (unsigned)f2bf(va.z) | ((unsigned)f2bf(va.w) << 16);
  unsigned p2 = (unsigned)f2bf(vb.x) | ((unsigned)f2bf(vb.y) << 16);
  unsigned p3 = (unsigned)f2bf(vb.z) | ((unsigned)f2bf(vb.w) << 16);
  *(uint4*)&xa[(size_t)n * 384 + 192 + s * 8] = make_uint4(p0, p1, p2, p3);
}

// ---------------------------------------------------------------------------
// CSR build via two-level LDS counting sort (no global atomics).
// ---------------------------------------------------------------------------
__global__ __launch_bounds__(256) void hist_kernel(
    const int* __restrict__ ei, int* __restrict__ cnt) {
  __shared__ int h[NBUK];
  int c = blockIdx.x, t = threadIdx.x;
  for (int i = t; i < NBUK; i += 256) h[i] = 0;
  __syncthreads();
  int e0 = c * CE;
  for (int e = e0 + t; e < e0 + CE; e += 256)
    atomicAdd(&h[ei[E_EDGES + e] >> 7], 1);
  __syncthreads();
  for (int i = t; i < NBUK; i += 256) cnt[i * NCHK + c] = h[i];
}

template <int LEN>
__global__ __launch_bounds__(256) void block_sum_kernel(
    const int* __restrict__ in, int* __restrict__ bsum) {
  __shared__ int sh[256];
  int i = blockIdx.x * 256 + threadIdx.x;
  sh[threadIdx.x] = (i < LEN) ? in[i] : 0;
  __syncthreads();
  for (int s = 128; s > 0; s >>= 1) {
    if (threadIdx.x < s) sh[threadIdx.x] += sh[threadIdx.x + s];
    __syncthreads();
  }
  if (threadIdx.x == 0) bsum[blockIdx.x] = sh[0];
}

__global__ __launch_bounds__(256) void scan_bsum_kernel(int* __restrict__ bsum) {
  __shared__ int sh[256];
  int t = threadIdx.x;
  sh[t] = (t < NB) ? bsum[t] : 0;
  __syncthreads();
  for (int off = 1; off < 256; off <<= 1) {
    int v = (t >= off) ? sh[t - off] : 0;
    __syncthreads();
    sh[t] += v;
    __syncthreads();
  }
  if (t < NB) bsum[t] = (t == 0) ? 0 : sh[t - 1];
}

template <int LEN>
__global__ __launch_bounds__(256) void scan_chunk_kernel(
    const int* __restrict__ in, const int* __restrict__ bsum,
    int* __restrict__ out) {
  __shared__ int sh[256];
  int t = threadIdx.x;
  int i = blockIdx.x * 256 + t;
  int v = (i < LEN) ? in[i] : 0;
  sh[t] = v;
  __syncthreads();
  for (int off = 1; off < 256; off <<= 1) {
    int u = (t >= off) ? sh[t - off] : 0;
    __syncthreads();
    sh[t] += u;
    __syncthreads();
  }
  if (i < LEN) out[i] = bsum[blockIdx.x] + sh[t] - v;  // exclusive
}

// Packed entry: (dst&127)<<16 | src  (src < 50000 < 2^16).
__global__ __launch_bounds__(256) void scatter_kernel(
    const int* __restrict__ ei, const int* __restrict__ ebase,
    unsigned* __restrict__ ebuf) {
  __shared__ int cur[NBUK];
  int c = blockIdx.x, t = threadIdx.x;
  for (int i = t; i < NBUK; i += 256) cur[i] = ebase[i * NCHK + c];
  __syncthreads();
  int e0 = c * CE;
  for (int e = e0 + t; e < e0 + CE; e += 256) {
    int s = ei[e], d = ei[E_EDGES + e];
    int p = atomicAdd(&cur[d >> 7], 1);
    ebuf[p] = ((unsigned)(d & 127) << 16) | (unsigned)s;
  }
}

// Per-bucket sort: writes deg/cursor; csr entries are BYTE OFFSETS into xa
// (src*768 + 384 = start of the x-part of the source row).
__global__ __launch_bounds__(256) void sortb_kernel(
    const unsigned* __restrict__ ebuf, const int* __restrict__ ebase,
    int* __restrict__ csr, int* __restrict__ deg, int* __restrict__ cursor) {
  __shared__ int h[128], sc[128], curn[128];
  int b = blockIdx.x, t = threadIdx.x;
  int beg = ebase[b * NCHK];
  int endb = (b == NBUK - 1) ? E_EDGES : ebase[(b + 1) * NCHK];
  if (t < 128) h[t] = 0;
  __syncthreads();
  for (int i = beg + t; i < endb; i += 256) atomicAdd(&h[ebuf[i] >> 16], 1);
  __syncthreads();
  if (t < 128) sc[t] = h[t];
  __syncthreads();
  for (int off = 1; off < 128; off <<= 1) {
    int v = (t >= off && t < 128) ? sc[t - off] : 0;
    __syncthreads();
    if (t < 128) sc[t] += v;
    __syncthreads();
  }
  if (t < 128) {
    curn[t] = sc[t] - h[t];
    int n = b * 128 + t;
    if (n < N_NODES) {
      deg[n] = h[t];
      cursor[n] = beg + sc[t];  // row end
    }
  }
  __syncthreads();
  for (int i = beg + t; i < endb; i += 256) {
    unsigned u = ebuf[i];
    int p = atomicAdd(&curn[u >> 16], 1);
    csr[beg + p] = (int)(u & 0xFFFFu) * 768 + 384;
  }
}

// ---------------------------------------------------------------------------
// Gather-aggregate: one wave per node; lane l<48 owns 4 channels (uint2/row).
// csr entries are byte offsets. 8-wide unroll for deep MLP.
// ---------------------------------------------------------------------------
__global__ __launch_bounds__(256) void gather_kernel(
    const int* __restrict__ csr, const int* __restrict__ cursor,
    const int* __restrict__ deg, unsigned short* __restrict__ xa) {
  int wid = (blockIdx.x * blockDim.x + threadIdx.x) >> 6;
  int lane = threadIdx.x & 63;
  if (wid >= N_NODES) return;
  int d = deg[wid];
  int end = cursor[wid];
  int start = end - d;
  const bool act = lane < 48;
  const char* base = (const char*)xa + (size_t)(lane * 8);

  float a0 = 0.f, a1 = 0.f, a2 = 0.f, a3 = 0.f;
  float b0 = 0.f, b1 = 0.f, b2 = 0.f, b3 = 0.f;
  int j = start;
  for (; j + 7 < end; j += 8) {
    int o0 = csr[j],     o1 = csr[j + 1], o2 = csr[j + 2], o3 = csr[j + 3];
    int o4 = csr[j + 4], o5 = csr[j + 5], o6 = csr[j + 6], o7 = csr[j + 7];
    if (act) {
      uint2 v0 = *(const uint2*)(base + o0);
      uint2 v1 = *(const uint2*)(base + o1);
      uint2 v2 = *(const uint2*)(base + o2);
      uint2 v3 = *(const uint2*)(base + o3);
      uint2 v4 = *(const uint2*)(base + o4);
      uint2 v5 = *(const uint2*)(base + o5);
      uint2 v6 = *(const uint2*)(base + o6);
      uint2 v7 = *(const uint2*)(base + o7);
      a0 += bflo32(v0.x) + bflo32(v2.x) + bflo32(v4.x) + bflo32(v6.x);
      a1 += bfhi32(v0.x) + bfhi32(v2.x) + bfhi32(v4.x) + bfhi32(v6.x);
      a2 += bflo32(v0.y) + bflo32(v2.y) + bflo32(v4.y) + bflo32(v6.y);
      a3 += bfhi32(v0.y) + bfhi32(v2.y) + bfhi32(v4.y) + bfhi32(v6.y);
      b0 += bflo32(v1.x) + bflo32(v3.x) + bflo32(v5.x) + bflo32(v7.x);
      b1 += bfhi32(v1.x) + bfhi32(v3.x) + bfhi32(v5.x) + bfhi32(v7.x);
      b2 += bflo32(v1.y) + bflo32(v3.y) + bflo32(v5.y) + bflo32(v7.y);
      b3 += bfhi32(v1.y) + bfhi32(v3.y) + bfhi32(v5.y) + bfhi32(v7.y);
    }
  }
  for (; j < end; ++j) {
    int o = csr[j];
    if (act) {
      uint2 v = *(const uint2*)(base + o);
      a0 += bflo32(v.x); a1 += bfhi32(v.x);
      a2 += bflo32(v.y); a3 += bfhi32(v.y);
    }
  }
  if (act) {
    float inv = 1.0f / fmaxf((float)d, 1.0f);
    float m0 = (a0 + b0) * inv, m1 = (a1 + b1) * inv;
    float m2 = (a2 + b2) * inv, m3 = (a3 + b3) * inv;
    unsigned r0 = (unsigned)f2bf(m0) | ((unsigned)f2bf(m1) << 16);
    unsigned r1 = (unsigned)f2bf(m2) | ((unsigned)f2bf(m3) << 16);
    *(uint2*)&xa[(size_t)wid * 384 + (size_t)lane * 4] = make_uint2(r0, r1);
  }
}

// ---------------------------------------------------------------------------
// Weight conversion (plain bf16, k-major per output column).
// ---------------------------------------------------------------------------
__global__ __launch_bounds__(256) void wconv_kernel(
    const float* __restrict__ Wl, const float* __restrict__ Wr,
    const float* __restrict__ W1, const float* __restrict__ W2,
    const float* __restrict__ W3, const float* __restrict__ W4,
    unsigned short* __restrict__ Wc_, unsigned short* __restrict__ W1_,
    unsigned short* __restrict__ W2_, unsigned short* __restrict__ W3_,
    unsigned short* __restrict__ W4_) {
  int idx = blockIdx.x * 256 + threadIdx.x;
  if (idx < 49152) {
    int k = idx % 192, m = idx / 192;
    Wc_[(size_t)m * 384 + k] = f2bf(Wl[(size_t)k * 256 + m]);
  } else if (idx < 98304) {
    int local = idx - 49152;
    int k = local % 192, m = local / 192;
    Wc_[(size_t)m * 384 + 192 + k] = f2bf(Wr[(size_t)k * 256 + m]);
  } else if (idx < 131072) {
    int local = idx - 98304;
    int k = local % 256, m = local / 256;
    W1_[(size_t)m * 256 + k] = f2bf(W1[(size_t)k * 128 + m]);
  } else if (idx < 139264) {
    int local = idx - 131072;
    int k = local % 128, m = local / 128;
    W2_[(size_t)m * 128 + k] = f2bf(W2[(size_t)k * 64 + m]);
  } else if (idx < 143360) {
    int local = idx - 139264;
    int k = local % 64, m = local / 64;
    W3_[(size_t)m * 64 + k] = f2bf(W3[(size_t)k * 64 + m]);
  } else if (idx < 151552) {
    int local = idx - 143360;
    int k = local % 64, m = local / 64;
    W4_[(size_t)m * 64 + k] = f2bf(W4[(size_t)k * 128 + m]);
  }
}

// ---------------------------------------------------------------------------
// Plain bf16 MFMA GEMM. PAIR=true: 1-D grid of 2*GRB blocks remapped so the
// two col-half blocks of one row stripe get linear IDs exactly 8 apart
// (= same XCD under round-robin) -> A stripe fetched into one L2.
// ---------------------------------------------------------------------------
template <int KBASE, int ALD, int OUTLD, int OUT_MODE, bool PAIR>
__global__ __launch_bounds__(256) void gemm_plain(
    const unsigned short* __restrict__ Ab, const unsigned short* __restrict__ Bb,
    const float* __restrict__ bias, const float* __restrict__ gamma,
    const float* __restrict__ beta, const float* __restrict__ bmean,
    const float* __restrict__ bvar, unsigned short* __restrict__ outp) {
  constexpr int BM = 128, BK = 64;
  constexpr int NITER = KBASE / BK;
  constexpr int GRB = NPAD / 128;  // 391

  __shared__ unsigned short lds[16384];  // 32 KB
  unsigned short* sA = lds;
  unsigned short* sB = lds + 8192;

  const int tid = threadIdx.x;
  const int wid = tid >> 6;
  const int lane = tid & 63;

  int rb, cb;
  if (PAIR) {
    int bid = blockIdx.x;
    int g = bid >> 4, r = bid & 15;
    int rem = GRB - g * 8; if (rem > 8) rem = 8;
    cb = (r >= rem) ? 1 : 0;
    rb = g * 8 + (cb ? r - rem : r);
  } else {
    rb = blockIdx.x; cb = 0;
  }
  const int rowbase = rb * BM;
  const int colbase = cb * 128;
  const int wr = wid >> 1, wc = wid & 1;

  f32x4 acc[4][4];
#pragma unroll
  for (int i = 0; i < 4; ++i)
#pragma unroll
    for (int j = 0; j < 4; ++j) acc[i][j] = (f32x4)0.f;

  for (int kt = 0; kt < NITER; ++kt) {
    const int kb = kt * BK;
    __syncthreads();
#pragma unroll
    for (int j = 0; j < 4; ++j) {
      int o = j * 4 + wid;
      int row = o * 8 + (lane >> 3);
      int slog = (lane & 7) ^ (lane >> 3);
      const char* src = (const char*)Bb +
          ((size_t)(colbase + row) * KBASE + kb) * 2 + (size_t)slog * 16;
      gload16(src, sB + o * 512);
    }
#pragma unroll
    for (int j = 0; j < 4; ++j) {
      int o = j * 4 + wid;
      int row = o * 8 + (lane >> 3);
      int slog = (lane & 7) ^ (lane >> 3);
      const char* src = (const char*)Ab +
          ((size_t)(rowbase + row) * ALD + kb) * 2 + (size_t)slog * 16;
      gload16(src, sA + o * 512);
    }
    __syncthreads();

#pragma unroll
    for (int kk = 0; kk < 2; ++kk) {
      short8v a[4], b[4];
#pragma unroll
      for (int fi = 0; fi < 4; ++fi) {
        int rt = wr * 64 + fi * 16 + (lane & 15);
        int sl = (kk * 4 + (lane >> 4)) ^ (rt & 7);
        a[fi] = *(const short8v*)&sA[rt * 64 + sl * 8];
      }
#pragma unroll
      for (int fj = 0; fj < 4; ++fj) {
        int ct = wc * 64 + fj * 16 + (lane & 15);
        int sl = (kk * 4 + (lane >> 4)) ^ (ct & 7);
        b[fj] = *(const short8v*)&sB[ct * 64 + sl * 8];
      }
#pragma unroll
      for (int fi = 0; fi < 4; ++fi)
#pragma unroll
        for (int fj = 0; fj < 4; ++fj)
          acc[fi][fj] = __builtin_amdgcn_mfma_f32_16x16x32_bf16(
              a[fi], b[fj], acc[fi][fj], 0, 0, 0);
    }
  }

  __syncthreads();
#pragma unroll
  for (int fj = 0; fj < 4; ++fj) {
    int gcl = wc * 64 + fj * 16 + (lane & 15);
    int gc = colbase + gcl;
    float sc, sh;
    if (OUT_MODE == 0) {
      float s = gamma[gc] * rsqrtf(bvar[gc] + BN_EPS);
      sc = s; sh = bias[gc] * s + beta[gc] - bmean[gc] * s;
    } else {
      sc = 1.f; sh = bias[gc];
    }
#pragma unroll
    for (int fi = 0; fi < 4; ++fi)
#pragma unroll
      for (int r = 0; r < 4; ++r) {
        int rt = wr * 64 + fi * 16 + ((lane >> 4) << 2) + r;
        float v = acc[fi][fj][r] * sc + sh;
        v = (v >= 0.f) ? v : SLOPE * v;
        lds[rt * 128 + gcl] = f2bf(v);
      }
  }
  __syncthreads();
#pragma unroll
  for (int i0 = 0; i0 < 8; ++i0) {
    int i = tid + i0 * 256;
    int row = i >> 4, u4 = i & 15;
    ((uint4*)(outp + (size_t)(rowbase + row) * OUTLD + colbase))[u4] =
        ((const uint4*)lds)[i];
  }
}

// ---------------------------------------------------------------------------
// Fused fc2+fc3+fc4 (unchanged).
// ---------------------------------------------------------------------------
__global__ __launch_bounds__(256) void fc234_kernel(
    const unsigned short* __restrict__ h1p,
    const unsigned short* __restrict__ W2_, const unsigned short* __restrict__ W3_,
    const unsigned short* __restrict__ W4_,
    const float* __restrict__ b2, const float* __restrict__ b3,
    const float* __restrict__ b4, float* __restrict__ outp) {
  __shared__ unsigned short lds[32768];
  unsigned short* SA  = lds;
  unsigned short* SB  = lds + 16384;
  unsigned short* SH2 = lds + 24576;

  const int tid = threadIdx.x;
  const int wid = tid >> 6;
  const int lane = tid & 63;
  const int rowbase = blockIdx.x * 128;
  const int wr = wid >> 1, wc = wid & 1;

#pragma unroll
  for (int j = 0; j < 8; ++j) {
    int o = j * 4 + wid;
    int rloc = o * 4 + (lane >> 4);
    int slog = (lane & 15) ^ ((rloc & 7) << 1);
    const char* src = (const char*)h1p +
        ((size_t)(rowbase + rloc) * 128) * 2 + (size_t)slog * 16;
    gload16(src, SA + o * 512);
  }
#pragma unroll
  for (int j = 0; j < 4; ++j) {
    int o = j * 4 + wid;
    int rloc = o * 4 + (lane >> 4);
    int slog = (lane & 15) ^ ((rloc & 7) << 1);
    const char* src = (const char*)W2_ +
        ((size_t)rloc * 128) * 2 + (size_t)slog * 16;
    gload16(src, SB + o * 512);
  }
  __syncthreads();

  f32x4 acc2[4][2];
#pragma unroll
  for (int i = 0; i < 4; ++i) { acc2[i][0] = (f32x4)0.f; acc2[i][1] = (f32x4)0.f; }
#pragma unroll
  for (int kk = 0; kk < 4; ++kk) {
    short8v a[4], b[2];
#pragma unroll
    for (int fi = 0; fi < 4; ++fi) {
      int rt = wr * 64 + fi * 16 + (lane & 15);
      int ph = (kk * 4 + (lane >> 4)) ^ ((rt & 7) << 1);
      a[fi] = *(const short8v*)&SA[rt * 128 + ph * 8];
    }
#pragma unroll
    for (int fj = 0; fj < 2; ++fj) {
      int ct = wc * 32 + fj * 16 + (lane & 15);
      int ph = (kk * 4 + (lane >> 4)) ^ ((ct & 7) << 1);
      b[fj] = *(const short8v*)&SB[ct * 128 + ph * 8];
    }
#pragma unroll
    for (int fi = 0; fi < 4; ++fi)
#pragma unroll
      for (int fj = 0; fj < 2; ++fj)
        acc2[fi][fj] = __builtin_amdgcn_mfma_f32_16x16x32_bf16(
            a[fi], b[fj], acc2[fi][fj], 0, 0, 0);
  }
  __syncthreads();

#pragma unroll
  for (int fj = 0; fj < 2; ++fj) {
    int gc = wc * 32 + fj * 16 + (lane & 15);
    float bb = b2[gc];
#pragma unroll
    for (int fi = 0; fi < 4; ++fi)
#pragma unroll
      for (int r = 0; r < 4; ++r) {
        int rt = wr * 64 + fi * 16 + ((lane >> 4) << 2) + r;
        float v = acc2[fi][fj][r] + bb;
        v = (v >= 0.f) ? v : SLOPE * v;
        SH2[rt * 64 + ((gc >> 3) ^ (rt & 7)) * 8 + (gc & 7)] = f2bf(v);
      }
  }
#pragma unroll
  for (int j = 0; j < 2; ++j) {
    int o = j * 4 + wid;
    int rloc = o * 8 + (lane >> 3);
    int slog = (lane & 7) ^ (lane >> 3);
    const char* src = (const char*)W3_ +
        ((size_t)rloc * 64) * 2 + (size_t)slog * 16;
    gload16(src, SB + o * 512);
  }
  __syncthreads();

  f32x4 acc3[4][2];
#pragma unroll
  for (int i = 0; i < 4; ++i) { acc3[i][0] = (f32x4)0.f; acc3[i][1] = (f32x4)0.f; }
#pragma unroll
  for (int kk = 0; kk < 2; ++kk) {
    short8v a[4], b[2];
#pragma unroll
    for (int fi = 0; fi < 4; ++fi) {
      int rt = wr * 64 + fi * 16 + (lane & 15);
      int ph = (kk * 4 + (lane >> 4)) ^ (rt & 7);
      a[fi] = *(const short8v*)&SH2[rt * 64 + ph * 8];
    }
#pragma unroll
    for (int fj = 0; fj < 2; ++fj) {
      int ct = wc * 32 + fj * 16 + (lane & 15);
      int ph = (kk * 4 + (lane >> 4)) ^ (ct & 7);
      b[fj] = *(const short8v*)&SB[ct * 64 + ph * 8];
    }
#pragma unroll
    for (int fi = 0; fi < 4; ++fi)
#pragma unroll
      for (int fj = 0; fj < 2; ++fj)
        acc3[fi][fj] = __builtin_amdgcn_mfma_f32_16x16x32_bf16(
            a[fi], b[fj], acc3[fi][fj], 0, 0, 0);
  }
  __syncthreads();

  unsigned short* SH3 = SA;
#pragma unroll
  for (int fj = 0; fj < 2; ++fj) {
    int gc = wc * 32 + fj * 16 + (lane & 15);
    float bb = b3[gc];
#pragma unroll
    for (int fi = 0; fi < 4; ++fi)
#pragma unroll
      for (int r = 0; r < 4; ++r) {
        int rt = wr * 64 + fi * 16 + ((lane >> 4) << 2) + r;
        float v = acc3[fi][fj][r] + bb;
        v = (v >= 0.f) ? v : SLOPE * v;
        SH3[rt * 64 + ((gc >> 3) ^ (rt & 7)) * 8 + (gc & 7)] = f2bf(v);
      }
  }
#pragma unroll
  for (int j = 0; j < 4; ++j) {
    int o = j * 4 + wid;
    int rloc = o * 8 + (lane >> 3);
    int slog = (lane & 7) ^ (lane >> 3);
    const char* src = (const char*)W4_ +
        ((size_t)rloc * 64) * 2 + (size_t)slog * 16;
    gload16(src, SB + o * 512);
  }
  __syncthreads();

  f32x4 acc4[4][4];
#pragma unroll
  for (int i = 0; i < 4; ++i)
#pragma unroll
    for (int j = 0; j < 4; ++j) acc4[i][j] = (f32x4)0.f;
#pragma unroll
  for (int kk = 0; kk < 2; ++kk) {
    short8v a[4], b[4];
#pragma unroll
    for (int fi = 0; fi < 4; ++fi) {
      int rt = wr * 64 + fi * 16 + (lane & 15);
      int ph = (kk * 4 + (lane >> 4)) ^ (rt & 7);
      a[fi] = *(const short8v*)&SH3[rt * 64 + ph * 8];
    }
#pragma unroll
    for (int fj = 0; fj < 4; ++fj) {
      int ct = wc * 64 + fj * 16 + (lane & 15);
      int ph = (kk * 4 + (lane >> 4)) ^ (ct & 7);
      b[fj] = *(const short8v*)&SB[ct * 64 + ph * 8];
    }
#pragma unroll
    for (int fi = 0; fi < 4; ++fi)
#pragma unroll
      for (int fj = 0; fj < 4; ++fj)
        acc4[fi][fj] = __builtin_amdgcn_mfma_f32_16x16x32_bf16(
            a[fi], b[fj], acc4[fi][fj], 0, 0, 0);
  }

  const int crow0 = rowbase + wr * 64;
#pragma unroll
  for (int fj = 0; fj < 4; ++fj) {
    int gc = wc * 64 + fj * 16 + (lane & 15);
    float bb = b4[gc];
#pragma unroll
    for (int fi = 0; fi < 4; ++fi)
#pragma unroll
      for (int r = 0; r < 4; ++r) {
        int gr = crow0 + fi * 16 + ((lane >> 4) << 2) + r;
        if (gr < N_NODES) {
          float v = acc4[fi][fj][r] + bb;
          v = (v >= 0.f) ? v : SLOPE * v;
          outp[(size_t)gr * FEAT + gc] = v;
        }
      }
  }
}

extern "C" void kernel_launch(void* const* d_in, const int* in_sizes, int n_in,
                              void* d_out, int out_size, void* d_ws, size_t ws_size,
                              hipStream_t stream) {
  const float* nf    = (const float*)d_in[0];
  const float* noise = (const float*)d_in[1];
  const int*   ei    = (const int*)d_in[2];
  const float* Wl    = (const float*)d_in[4];
  const float* bl    = (const float*)d_in[5];
  const float* Wr    = (const float*)d_in[6];
  const float* gam   = (const float*)d_in[7];
  const float* bet   = (const float*)d_in[8];
  const float* bmean = (const float*)d_in[9];
  const float* bvar  = (const float*)d_in[10];
  const float* fc1w  = (const float*)d_in[11];
  const float* fc1b  = (const float*)d_in[12];
  const float* fc2w  = (const float*)d_in[13];
  const float* fc2b  = (const float*)d_in[14];
  const float* fc3w  = (const float*)d_in[15];
  const float* fc3b  = (const float*)d_in[16];
  const float* fc4w  = (const float*)d_in[17];
  const float* fc4b  = (const float*)d_in[18];
  float* outp = (float*)d_out;

  // ---- workspace (ushort units unless noted) ----
  unsigned short* xa  = (unsigned short*)d_ws;             // [NPAD][384]: [agg|x]
  unsigned short* hp  = xa + (size_t)NPAD * 384;           // [NPAD][256]
  unsigned short* Wc_ = hp + (size_t)NPAD * 256;           // 256*384
  unsigned short* W1_ = Wc_ + 256 * 384;                   // 128*256
  unsigned short* W2_ = W1_ + 128 * 256;                   // 64*128
  unsigned short* W3_ = W2_ + 64 * 128;                    // 64*64
  unsigned short* W4_ = W3_ + 64 * 64;                     // 128*64
  int* deg    = (int*)(W4_ + 128 * 64);                    // N
  int* cursor = deg + N_NODES;                             // N
  int* bsum   = cursor + N_NODES;                          // 256
  int* cnt    = bsum + 256;                                // NBUK*NCHK
  int* ebase  = cnt + NBUK * NCHK;                         // NBUK*NCHK
  unsigned short* h1p = xa;                                // [NPAD][128]
  int*      csr  = (int*)d_out;                            // E ints (scratch)
  unsigned* ebuf = (unsigned*)d_out + E_EDGES;             // E uints (scratch)

  wconv_kernel<<<592, 256, 0, stream>>>(Wl, Wr, fc1w, fc2w, fc3w, fc4w,
                                        Wc_, W1_, W2_, W3_, W4_);
  xconv_kernel<<<(N_NODES * 24 + 255) / 256, 256, 0, stream>>>(nf, noise, xa);

  // --- CSR build: LDS counting sort, no global atomics ---
  hist_kernel<<<NCHK, 256, 0, stream>>>(ei, cnt);
  block_sum_kernel<NBUK * NCHK><<<NB, 256, 0, stream>>>(cnt, bsum);
  scan_bsum_kernel<<<1, 256, 0, stream>>>(bsum);
  scan_chunk_kernel<NBUK * NCHK><<<NB, 256, 0, stream>>>(cnt, bsum, ebase);
  scatter_kernel<<<NCHK, 256, 0, stream>>>(ei, ebase, ebuf);
  sortb_kernel<<<NBUK, 256, 0, stream>>>(ebuf, ebase, csr, deg, cursor);

  // --- Aggregate ---
  gather_kernel<<<(N_NODES + 3) / 4, 256, 0, stream>>>(csr, cursor, deg, xa);

  const int RB = NPAD / 128;  // 391

  // --- combine: K=384, 2*RB paired blocks, out 256 cols + BN+lrelu ---
  gemm_plain<384, 384, 256, 0, true><<<2 * RB, 256, 0, stream>>>(
      xa, Wc_, bl, gam, bet, bmean, bvar, hp);
  // --- fc1: K=256, out 128 cols + bias+lrelu ---
  gemm_plain<256, 256, 128, 1, false><<<RB, 256, 0, stream>>>(
      hp, W1_, fc1b, nullptr, nullptr, nullptr, nullptr, h1p);
  // --- fused fc2+fc3+fc4 -> f32 out ---
  fc234_kernel<<<RB, 256, 0, stream>>>(h1p, W2_, W3_, W4_,
                                       fc2b, fc3b, fc4b, outp);
}